// Round 1
// baseline (776.028 us; speedup 1.0000x reference)
//
#include <hip/hip_runtime.h>
#include <hip/hip_bf16.h>
#include <math.h>

// ---------------------------------------------------------------------------
// Transformer block fwd: B=4,T=2048,D=1024,H=16,HS=64,FF=4096, fp32 in/out,
// bf16 MFMA internally. Residual path (x, h, out) kept fp32.
// Workspace required ~202 MB.
// ---------------------------------------------------------------------------

typedef unsigned short u16;
typedef __attribute__((ext_vector_type(8))) short s16x8;   // 8 x bf16 (4 VGPR)
typedef __attribute__((ext_vector_type(4))) float f32x4;   // MFMA acc

__device__ __forceinline__ u16 f2bf(float f) {
    unsigned u = __float_as_uint(f);
    u += 0x7fffu + ((u >> 16) & 1u);      // round-to-nearest-even
    return (u16)(u >> 16);
}
__device__ __forceinline__ float gelu_f(float v) {
    return 0.5f * v * (1.0f + erff(v * 0.70710678118654752f));
}

// --------------------------- weight transpose ------------------------------
// in: fp32 [K,N] row-major  ->  out: bf16 [N,K] row-major
__global__ __launch_bounds__(256) void transpose_f32_bf16(
    const float* __restrict__ in, u16* __restrict__ out, int K, int N) {
    __shared__ float t[32][33];
    int n0 = blockIdx.x * 32, k0 = blockIdx.y * 32;
    int c = threadIdx.x, r0 = threadIdx.y;           // block (32,8)
#pragma unroll
    for (int i = 0; i < 4; i++) {
        int r = r0 + i * 8;
        t[r][c] = in[(size_t)(k0 + r) * N + n0 + c];
    }
    __syncthreads();
#pragma unroll
    for (int i = 0; i < 4; i++) {
        int r = r0 + i * 8;
        out[(size_t)(n0 + r) * K + k0 + c] = f2bf(t[c][r]);
    }
}

// ------------------------------ layernorm ----------------------------------
// in fp32 [rows,1024] -> out bf16 (optionally exact GELU after LN)
template <bool GELU>
__global__ __launch_bounds__(256) void ln_kernel(
    const float* __restrict__ x, const float* __restrict__ g,
    const float* __restrict__ bt, u16* __restrict__ out) {
    const int D = 1024;
    int row = blockIdx.x;
    float4 v = reinterpret_cast<const float4*>(x + (size_t)row * D)[threadIdx.x];
    float s = v.x + v.y + v.z + v.w;
    float s2 = v.x * v.x + v.y * v.y + v.z * v.z + v.w * v.w;
#pragma unroll
    for (int off = 32; off > 0; off >>= 1) {
        s += __shfl_down(s, off);
        s2 += __shfl_down(s2, off);
    }
    __shared__ float red[8];
    int wid = threadIdx.x >> 6;
    if ((threadIdx.x & 63) == 0) { red[wid] = s; red[wid + 4] = s2; }
    __syncthreads();
    s = red[0] + red[1] + red[2] + red[3];
    s2 = red[4] + red[5] + red[6] + red[7];
    float mu = s * (1.0f / 1024.0f);
    float var = s2 * (1.0f / 1024.0f) - mu * mu;
    float rstd = rsqrtf(var + 1e-5f);
    float4 gg = reinterpret_cast<const float4*>(g)[threadIdx.x];
    float4 bb = reinterpret_cast<const float4*>(bt)[threadIdx.x];
    float o0 = (v.x - mu) * rstd * gg.x + bb.x;
    float o1 = (v.y - mu) * rstd * gg.y + bb.y;
    float o2 = (v.z - mu) * rstd * gg.z + bb.z;
    float o3 = (v.w - mu) * rstd * gg.w + bb.w;
    if (GELU) { o0 = gelu_f(o0); o1 = gelu_f(o1); o2 = gelu_f(o2); o3 = gelu_f(o3); }
    ushort4 o;
    o.x = f2bf(o0); o.y = f2bf(o1); o.z = f2bf(o2); o.w = f2bf(o3);
    reinterpret_cast<ushort4*>(out + (size_t)row * D)[threadIdx.x] = o;
}

// -------------------------------- GEMM -------------------------------------
// C[M,N] = A[M,K](bf16) * B (given as BT[N,K] bf16) + bias; optional GELU;
// optional fp32 residual add; out bf16 or fp32.
// 128x128 tile, BK=32, 256 thr (4 waves 2x2), mfma_f32_16x16x32_bf16.
template <int OUT_BF16, int ACT_GELU, int HAS_RES>
__global__ __launch_bounds__(256) void gemm_kernel(
    const u16* __restrict__ A, const u16* __restrict__ BT,
    const float* __restrict__ bias, const float* __restrict__ res,
    void* __restrict__ outp, int M, int N, int K) {
    constexpr int LDA = 40;  // +8 pad: 2-way LDS conflicts only (free)
    __shared__ u16 As[128 * LDA];
    __shared__ u16 Bs[128 * LDA];
    const int m0 = blockIdx.y * 128, n0 = blockIdx.x * 128;
    const int tid = threadIdx.x;
    const int w = tid >> 6, lane = tid & 63, l16 = lane & 15, quad = lane >> 4;
    const int wm = (w >> 1) * 64, wn = (w & 1) * 64;

    f32x4 acc[4][4] = {};

    for (int k0 = 0; k0 < K; k0 += 32) {
        __syncthreads();
#pragma unroll
        for (int s = 0; s < 2; s++) {
            int v = tid + s * 256;                 // 512 vec8 loads per tile pair
            int row = v >> 2, cv = (v & 3) * 8;
            *(s16x8*)&As[row * LDA + cv] =
                *(const s16x8*)&A[(size_t)(m0 + row) * K + k0 + cv];
            *(s16x8*)&Bs[row * LDA + cv] =
                *(const s16x8*)&BT[(size_t)(n0 + row) * K + k0 + cv];
        }
        __syncthreads();
        s16x8 af[4], bf[4];
#pragma unroll
        for (int i = 0; i < 4; i++)
            af[i] = *(const s16x8*)&As[(wm + i * 16 + l16) * LDA + quad * 8];
#pragma unroll
        for (int j = 0; j < 4; j++)
            bf[j] = *(const s16x8*)&Bs[(wn + j * 16 + l16) * LDA + quad * 8];
#pragma unroll
        for (int i = 0; i < 4; i++)
#pragma unroll
            for (int j = 0; j < 4; j++)
                acc[i][j] = __builtin_amdgcn_mfma_f32_16x16x32_bf16(
                    af[i], bf[j], acc[i][j], 0, 0, 0);
    }

    float bv[4];
#pragma unroll
    for (int j = 0; j < 4; j++) bv[j] = bias[n0 + wn + j * 16 + l16];
#pragma unroll
    for (int i = 0; i < 4; i++) {
        int rowb = m0 + wm + i * 16 + quad * 4;
#pragma unroll
        for (int j = 0; j < 4; j++) {
            int col = n0 + wn + j * 16 + l16;
#pragma unroll
            for (int r = 0; r < 4; r++) {
                float v = acc[i][j][r] + bv[j];
                if (ACT_GELU) v = gelu_f(v);
                size_t idx = (size_t)(rowb + r) * N + col;
                if (HAS_RES) v += res[idx];
                if (OUT_BF16) ((u16*)outp)[idx] = f2bf(v);
                else          ((float*)outp)[idx] = v;
            }
        }
    }
}

// ----------------------------- flash attention -----------------------------
// qkv bf16 [B*T, 3072]  (cols: Q | K | V, head h owns 64 cols each)
// o   bf16 [B*T, 1024]
// grid (B*H=64, T/64=32), block 256 = 4 waves; wave w owns 16 q rows.
__global__ __launch_bounds__(256) void attn_kernel(
    const u16* __restrict__ qkv, u16* __restrict__ o) {
    const int T = 2048, D3 = 3072, Dm = 1024;
    const int bh = blockIdx.x, qb = blockIdx.y;
    const int b = bh >> 4, h = bh & 15;
    const int tid = threadIdx.x;
    const int w = tid >> 6, lane = tid & 63, l16 = lane & 15, quad = lane >> 4;
    const size_t tokbase = (size_t)b * T;

    __shared__ u16 Ks[64 * 72];        // K tile [key][dim]
    __shared__ u16 Vt[64 * 72];        // V tile transposed [dim][key], seg-skewed
    __shared__ u16 Ps[4][16 * 72];     // per-wave P tile [q][key]

    // Q fragments (A-layout), loaded once, direct from global
    s16x8 aq[2];
    {
        int qrow = qb * 64 + w * 16 + l16;
        const u16* qp = qkv + (tokbase + qrow) * D3 + h * 64 + quad * 8;
        aq[0] = *(const s16x8*)(qp);
        aq[1] = *(const s16x8*)(qp + 32);
    }

    f32x4 acc_o[4] = {};
    float m_i[4], l_i[4];
#pragma unroll
    for (int r = 0; r < 4; r++) { m_i[r] = -1e30f; l_i[r] = 0.f; }
    const float scale = 0.125f;  // 1/sqrt(64)

    for (int kt = 0; kt < T / 64; kt++) {
        __syncthreads();  // previous iteration's PV reads done
#pragma unroll
        for (int s = 0; s < 2; s++) {
            int v = tid + s * 256;
            int row = v >> 3, cv = (v & 7) * 8;   // row=key, cv=dim base
            const u16* kp = qkv + (tokbase + kt * 64 + row) * D3 + 1024 + h * 64 + cv;
            *(s16x8*)&Ks[row * 72 + cv] = *(const s16x8*)kp;
            s16x8 vv = *(const s16x8*)(kp + 1024);
#pragma unroll
            for (int i = 0; i < 8; i++) {
                int dim = cv + i;
                // seg-skew: breaks the 16-way write conflict, reads stay b128
                Vt[dim * 72 + ((row + (dim >> 3) * 8) & 63)] =
                    ((const u16*)&vv)[i];
            }
        }
        __syncthreads();

        // S = Q K^T  (16q x 64k per wave)
        f32x4 acc_s[4] = {};
#pragma unroll
        for (int ks = 0; ks < 2; ks++)
#pragma unroll
            for (int sub = 0; sub < 4; sub++) {
                s16x8 bk = *(const s16x8*)&Ks[(sub * 16 + l16) * 72 + ks * 32 + quad * 8];
                acc_s[sub] = __builtin_amdgcn_mfma_f32_16x16x32_bf16(
                    aq[ks], bk, acc_s[sub], 0, 0, 0);
            }

        // online softmax; row r of this quad = q (quad*4+r)
        float p[4][4], alpha[4];
#pragma unroll
        for (int r = 0; r < 4; r++) {
            float mx = fmaxf(fmaxf(acc_s[0][r], acc_s[1][r]),
                             fmaxf(acc_s[2][r], acc_s[3][r])) * scale;
#pragma unroll
            for (int off = 1; off < 16; off <<= 1) mx = fmaxf(mx, __shfl_xor(mx, off));
            float mnew = fmaxf(m_i[r], mx);
            float a = __expf(m_i[r] - mnew);
            float rs = 0.f;
#pragma unroll
            for (int sub = 0; sub < 4; sub++) {
                float pv = __expf(acc_s[sub][r] * scale - mnew);
                p[sub][r] = pv; rs += pv;
            }
#pragma unroll
            for (int off = 1; off < 16; off <<= 1) rs += __shfl_xor(rs, off);
            m_i[r] = mnew;
            l_i[r] = l_i[r] * a + rs;
            alpha[r] = a;
        }
#pragma unroll
        for (int d = 0; d < 4; d++)
#pragma unroll
            for (int r = 0; r < 4; r++) acc_o[d][r] *= alpha[r];

        // P: C/D layout -> LDS -> A layout
#pragma unroll
        for (int sub = 0; sub < 4; sub++)
#pragma unroll
            for (int r = 0; r < 4; r++)
                Ps[w][(quad * 4 + r) * 72 + sub * 16 + l16] = f2bf(p[sub][r]);
        __syncthreads();  // conservative: guarantees P writes visible (all waves in lockstep)

        // O += P V
#pragma unroll
        for (int ks = 0; ks < 2; ks++) {
            s16x8 ap = *(const s16x8*)&Ps[w][l16 * 72 + ks * 32 + quad * 8];
#pragma unroll
            for (int d = 0; d < 4; d++) {
                int dim = d * 16 + l16;
                int blk = (ks * 4 + quad + (dim >> 3)) & 7;
                s16x8 bvv = *(const s16x8*)&Vt[dim * 72 + blk * 8];
                acc_o[d] = __builtin_amdgcn_mfma_f32_16x16x32_bf16(
                    ap, bvv, acc_o[d], 0, 0, 0);
            }
        }
    }

    // epilogue: O / l  -> o[token][h*64+dim]
#pragma unroll
    for (int d = 0; d < 4; d++)
#pragma unroll
        for (int r = 0; r < 4; r++) {
            float v = acc_o[d][r] / l_i[r];
            int trow = qb * 64 + w * 16 + quad * 4 + r;
            o[(tokbase + trow) * Dm + h * 64 + d * 16 + l16] = f2bf(v);
        }
}

// ------------------------------- launcher ----------------------------------
extern "C" void kernel_launch(void* const* d_in, const int* in_sizes, int n_in,
                              void* d_out, int out_size, void* d_ws, size_t ws_size,
                              hipStream_t stream) {
    const int M = 8192;   // B*T
    const int D = 1024, D3 = 3072, FF = 4096;

    const float* x      = (const float*)d_in[0];
    const float* ln1_g  = (const float*)d_in[1];
    const float* ln1_b  = (const float*)d_in[2];
    const float* W_ap   = (const float*)d_in[3];
    const float* b_ap   = (const float*)d_in[4];
    const float* W_qkv  = (const float*)d_in[5];
    const float* b_qkv  = (const float*)d_in[6];
    const float* W_proj = (const float*)d_in[7];
    const float* b_proj = (const float*)d_in[8];
    const float* ln2_g  = (const float*)d_in[9];
    const float* ln2_b  = (const float*)d_in[10];
    const float* W1     = (const float*)d_in[11];
    const float* b1     = (const float*)d_in[12];
    const float* W2     = (const float*)d_in[13];
    const float* b2     = (const float*)d_in[14];

    // workspace carve (all offsets 256B aligned)
    char* p = (char*)d_ws;
    auto carve = [&](size_t bytes) { char* r = p; p += (bytes + 255) & ~(size_t)255; return r; };
    u16*   WapT   = (u16*)carve((size_t)D * D * 2);
    u16*   WqkvT  = (u16*)carve((size_t)D * D3 * 2);
    u16*   WprojT = (u16*)carve((size_t)D * D * 2);
    u16*   W1T    = (u16*)carve((size_t)D * FF * 2);
    u16*   W2T    = (u16*)carve((size_t)FF * D * 2);
    u16*   aln    = (u16*)carve((size_t)M * D * 2);    // reused as gbuf
    u16*   a1     = (u16*)carve((size_t)M * D * 2);    // reused as obuf
    u16*   qkvb   = (u16*)carve((size_t)M * D3 * 2);
    float* hbuf   = (float*)carve((size_t)M * D * 4);
    u16*   f1     = (u16*)carve((size_t)M * FF * 2);
    u16* gbuf = aln;
    u16* obuf = a1;

    dim3 tb(32, 8);
    transpose_f32_bf16<<<dim3(D / 32, D / 32), tb, 0, stream>>>(W_ap, WapT, D, D);
    transpose_f32_bf16<<<dim3(D3 / 32, D / 32), tb, 0, stream>>>(W_qkv, WqkvT, D, D3);
    transpose_f32_bf16<<<dim3(D / 32, D / 32), tb, 0, stream>>>(W_proj, WprojT, D, D);
    transpose_f32_bf16<<<dim3(FF / 32, D / 32), tb, 0, stream>>>(W1, W1T, D, FF);
    transpose_f32_bf16<<<dim3(D / 32, FF / 32), tb, 0, stream>>>(W2, W2T, FF, D);

    // a = LN1(x)
    ln_kernel<false><<<M, 256, 0, stream>>>(x, ln1_g, ln1_b, aln);
    // a1 = a @ W_ap + b_ap
    gemm_kernel<1, 0, 0><<<dim3(D / 128, M / 128), 256, 0, stream>>>(
        aln, WapT, b_ap, nullptr, a1, M, D, D);
    // qkv = a1 @ W_qkv + b_qkv
    gemm_kernel<1, 0, 0><<<dim3(D3 / 128, M / 128), 256, 0, stream>>>(
        a1, WqkvT, b_qkv, nullptr, qkvb, M, D3, D);
    // o = attention(qkv)
    attn_kernel<<<dim3(64, 32), 256, 0, stream>>>(qkvb, obuf);
    // h = x + o @ W_proj + b_proj   (fp32)
    gemm_kernel<0, 0, 1><<<dim3(D / 128, M / 128), 256, 0, stream>>>(
        obuf, WprojT, b_proj, x, hbuf, M, D, D);
    // g = gelu(LN2(h))
    ln_kernel<true><<<M, 256, 0, stream>>>(hbuf, ln2_g, ln2_b, gbuf);
    // f1 = gelu(g @ W1 + b1)
    gemm_kernel<1, 1, 0><<<dim3(FF / 128, M / 128), 256, 0, stream>>>(
        gbuf, W1T, b1, nullptr, f1, M, FF, D);
    // out = h + f1 @ W2 + b2   (fp32)
    gemm_kernel<0, 0, 1><<<dim3(D / 128, M / 128), 256, 0, stream>>>(
        f1, W2T, b2, hbuf, (float*)d_out, M, D, FF);
}

// Round 2
// 714.042 us; speedup vs baseline: 1.0868x; 1.0868x over previous
//
#include <hip/hip_runtime.h>
#include <hip/hip_bf16.h>
#include <math.h>

// ---------------------------------------------------------------------------
// Transformer block fwd: B=4,T=2048,D=1024,H=16,HS=64,FF=4096, fp32 in/out,
// bf16 MFMA internally. Residual path (x, h, out) kept fp32.
// R1: m97-style GEMM (global_load_lds w16, unpadded LDS), S^T/O^T flash attn
//     (lane-local softmax, vectorized P/V paths), V written pre-transposed
//     by the qkv GEMM epilogue.
// ---------------------------------------------------------------------------

typedef unsigned short u16;
typedef __attribute__((ext_vector_type(8))) short s16x8;   // 8 x bf16 (4 VGPR)
typedef __attribute__((ext_vector_type(4))) float f32x4;   // MFMA acc

__device__ __forceinline__ u16 f2bf(float f) {
    unsigned u = __float_as_uint(f);
    u += 0x7fffu + ((u >> 16) & 1u);      // round-to-nearest-even
    return (u16)(u >> 16);
}
__device__ __forceinline__ float gelu_f(float v) {
    return 0.5f * v * (1.0f + erff(v * 0.70710678118654752f));
}
// async global->LDS, 16B per lane; lds pointer must be wave-uniform.
__device__ __forceinline__ void glds16(const u16* g, u16* l) {
    __builtin_amdgcn_global_load_lds(
        (const __attribute__((address_space(1))) void*)g,
        (__attribute__((address_space(3))) void*)l, 16, 0, 0);
}

// --------------------------- weight transpose ------------------------------
__global__ __launch_bounds__(256) void transpose_f32_bf16(
    const float* __restrict__ in, u16* __restrict__ out, int K, int N) {
    __shared__ float t[32][33];
    int n0 = blockIdx.x * 32, k0 = blockIdx.y * 32;
    int c = threadIdx.x, r0 = threadIdx.y;           // block (32,8)
#pragma unroll
    for (int i = 0; i < 4; i++) {
        int r = r0 + i * 8;
        t[r][c] = in[(size_t)(k0 + r) * N + n0 + c];
    }
    __syncthreads();
#pragma unroll
    for (int i = 0; i < 4; i++) {
        int r = r0 + i * 8;
        out[(size_t)(n0 + r) * K + k0 + c] = f2bf(t[c][r]);
    }
}

// ------------------------------ layernorm ----------------------------------
template <bool GELU>
__global__ __launch_bounds__(256) void ln_kernel(
    const float* __restrict__ x, const float* __restrict__ g,
    const float* __restrict__ bt, u16* __restrict__ out) {
    const int D = 1024;
    int row = blockIdx.x;
    float4 v = reinterpret_cast<const float4*>(x + (size_t)row * D)[threadIdx.x];
    float s = v.x + v.y + v.z + v.w;
    float s2 = v.x * v.x + v.y * v.y + v.z * v.z + v.w * v.w;
#pragma unroll
    for (int off = 32; off > 0; off >>= 1) {
        s += __shfl_down(s, off);
        s2 += __shfl_down(s2, off);
    }
    __shared__ float red[8];
    int wid = threadIdx.x >> 6;
    if ((threadIdx.x & 63) == 0) { red[wid] = s; red[wid + 4] = s2; }
    __syncthreads();
    s = red[0] + red[1] + red[2] + red[3];
    s2 = red[4] + red[5] + red[6] + red[7];
    float mu = s * (1.0f / 1024.0f);
    float var = s2 * (1.0f / 1024.0f) - mu * mu;
    float rstd = rsqrtf(var + 1e-5f);
    float4 gg = reinterpret_cast<const float4*>(g)[threadIdx.x];
    float4 bb = reinterpret_cast<const float4*>(bt)[threadIdx.x];
    float o0 = (v.x - mu) * rstd * gg.x + bb.x;
    float o1 = (v.y - mu) * rstd * gg.y + bb.y;
    float o2 = (v.z - mu) * rstd * gg.z + bb.z;
    float o3 = (v.w - mu) * rstd * gg.w + bb.w;
    if (GELU) { o0 = gelu_f(o0); o1 = gelu_f(o1); o2 = gelu_f(o2); o3 = gelu_f(o3); }
    ushort4 o;
    o.x = f2bf(o0); o.y = f2bf(o1); o.z = f2bf(o2); o.w = f2bf(o3);
    reinterpret_cast<ushort4*>(out + (size_t)row * D)[threadIdx.x] = o;
}

// -------------------------------- GEMM -------------------------------------
// C[M,N] = A[M,K](bf16) * BT[N,K](bf16) + bias; optional GELU / fp32 residual;
// out bf16 or fp32. 128x128 tile, BK=32, 4 waves 2x2, mfma 16x16x32.
// m97 structure: unpadded stride-32 LDS, global_load_lds width=16 staging.
// SPLIT_V: blocks with n0>=2048 (V third of qkv) write transposed to vtg
//          [b,h,dim,t] instead (4 consecutive tokens -> one b64 store).
template <int OUT_BF16, int ACT_GELU, int HAS_RES, int SPLIT_V>
__global__ __launch_bounds__(256) void gemm_kernel(
    const u16* __restrict__ A, const u16* __restrict__ BT,
    const float* __restrict__ bias, const float* __restrict__ res,
    void* __restrict__ outp, u16* __restrict__ vtg, int M, int N, int K) {
    __shared__ u16 As[128 * 32];
    __shared__ u16 Bs[128 * 32];
    const int m0 = blockIdx.y * 128, n0 = blockIdx.x * 128;
    const int tid = threadIdx.x;
    const int w = tid >> 6, lane = tid & 63, l16 = lane & 15, quad = lane >> 4;
    const int wm = (w >> 1) * 64, wn = (w & 1) * 64;

    // staging: wave w covers rows [w*32, w*32+32); chunk c covers 16 rows.
    // lane i -> row base + i/4, col (i%4)*8  (matches lane-contiguous LDS dest)
    const int srow = w * 32 + (lane >> 2);
    const int scol = (lane & 3) * 8;
    const u16* Ag = A + (size_t)(m0 + srow) * K + scol;
    const u16* Bg = BT + (size_t)(n0 + srow) * K + scol;
    u16* Asl = &As[(w * 32) * 32];     // wave-uniform LDS bases
    u16* Bsl = &Bs[(w * 32) * 32];

    f32x4 acc[4][4] = {};

    for (int k0 = 0; k0 < K; k0 += 32) {
        __syncthreads();                       // prev frag reads done
        glds16(Ag + k0, Asl);
        glds16(Ag + k0 + (size_t)16 * K, Asl + 16 * 32);
        glds16(Bg + k0, Bsl);
        glds16(Bg + k0 + (size_t)16 * K, Bsl + 16 * 32);
        __syncthreads();                       // drains vmcnt (staging visible)
        s16x8 af[4], bf[4];
#pragma unroll
        for (int i = 0; i < 4; i++)
            af[i] = *(const s16x8*)&As[(wm + i * 16 + l16) * 32 + quad * 8];
#pragma unroll
        for (int j = 0; j < 4; j++)
            bf[j] = *(const s16x8*)&Bs[(wn + j * 16 + l16) * 32 + quad * 8];
#pragma unroll
        for (int i = 0; i < 4; i++)
#pragma unroll
            for (int j = 0; j < 4; j++)
                acc[i][j] = __builtin_amdgcn_mfma_f32_16x16x32_bf16(
                    af[i], bf[j], acc[i][j], 0, 0, 0);
    }

    float bv[4];
#pragma unroll
    for (int j = 0; j < 4; j++) bv[j] = bias[n0 + wn + j * 16 + l16];

    if (SPLIT_V && n0 >= 2048) {
        // V region: write transposed vtg[(b*1024 + vcol)*2048 + t], 4 tokens/b64
#pragma unroll
        for (int i = 0; i < 4; i++) {
            int rowb = m0 + wm + i * 16 + quad * 4;
            int bb = rowb >> 11, tt = rowb & 2047;
#pragma unroll
            for (int j = 0; j < 4; j++) {
                int vcol = n0 + wn + j * 16 + l16 - 2048;
                ushort4 pk;
                pk.x = f2bf(acc[i][j][0] + bv[j]);
                pk.y = f2bf(acc[i][j][1] + bv[j]);
                pk.z = f2bf(acc[i][j][2] + bv[j]);
                pk.w = f2bf(acc[i][j][3] + bv[j]);
                *(ushort4*)&vtg[((size_t)bb * 1024 + vcol) * 2048 + tt] = pk;
            }
        }
    } else {
#pragma unroll
        for (int i = 0; i < 4; i++) {
            int rowb = m0 + wm + i * 16 + quad * 4;
#pragma unroll
            for (int j = 0; j < 4; j++) {
                int col = n0 + wn + j * 16 + l16;
#pragma unroll
                for (int r = 0; r < 4; r++) {
                    float v = acc[i][j][r] + bv[j];
                    if (ACT_GELU) v = gelu_f(v);
                    size_t idx = (size_t)(rowb + r) * N + col;
                    if (HAS_RES) v += res[idx];
                    if (OUT_BF16) ((u16*)outp)[idx] = f2bf(v);
                    else          ((float*)outp)[idx] = v;
                }
            }
        }
    }
}

// ----------------------------- flash attention -----------------------------
// S^T/O^T formulation: S^T[key][q] = K·Q^T so C/D gives q = lane&15 (one
// softmax row per lane); O^T[dim][q] = V^T·P^T reuses the P fragment as B.
// qkv bf16 [B*T,3072] (Q cols 0..1023, K cols 1024..2047; V third unwritten),
// vtg bf16 [b,h,dim,2048], o bf16 [B*T,1024].
// grid (qb=32, bh=64) — qb fast for K/V L2 locality; block 256 = 4 waves.
__global__ __launch_bounds__(256) void attn_kernel(
    const u16* __restrict__ qkv, const u16* __restrict__ vtg,
    u16* __restrict__ o) {
    const int T = 2048, D3 = 3072, Dm = 1024;
    const int qb = blockIdx.x, bh = blockIdx.y;
    const int b = bh >> 4, h = bh & 15;
    const int tid = threadIdx.x;
    const int w = tid >> 6, lane = tid & 63, l16 = lane & 15, quad = lane >> 4;
    const size_t tokbase = (size_t)b * T;

    __shared__ u16 Ks[64 * 72];        // K tile [key][dim]
    __shared__ u16 Vts[64 * 72];       // V^T tile [dim][key]
    __shared__ u16 Pt[4][16 * 72];     // per-wave P^T as [q][key]

    // Q fragment (B operand: n=q=l16, k=dim=quad*8+j)
    s16x8 bq[2];
    {
        int qrow = qb * 64 + w * 16 + l16;
        const u16* qp = qkv + (tokbase + qrow) * D3 + h * 64 + quad * 8;
        bq[0] = *(const s16x8*)qp;
        bq[1] = *(const s16x8*)(qp + 32);
    }

    f32x4 acc_ot[4] = {};
    float m_i = -1e30f, l_i = 0.f;
    const float s2 = 0.125f * 1.44269504088896f;   // scale * log2(e)

    const u16* kgbase = qkv + tokbase * D3 + 1024 + h * 64;
    const u16* vgbase = vtg + ((size_t)b * 1024 + h * 64) * T;

    const int srow = tid >> 3;           // 0..31 (+32 in 2nd segment)
    const int scv = (tid & 7) * 8;

    for (int kt = 0; kt < 32; kt++) {
        __syncthreads();                 // prev PV reads done
#pragma unroll
        for (int s = 0; s < 2; s++) {
            int row = srow + s * 32;
            *(s16x8*)&Ks[row * 72 + scv] =
                *(const s16x8*)(kgbase + (size_t)(kt * 64 + row) * D3 + scv);
            *(s16x8*)&Vts[row * 72 + scv] =
                *(const s16x8*)(vgbase + (size_t)row * T + kt * 64 + scv);
        }
        __syncthreads();

        // S^T = K Q^T : 4 key-tiles of 16, K-dim 64 = 2 mfmas each
        f32x4 st[4] = {};
#pragma unroll
        for (int kd = 0; kd < 2; kd++)
#pragma unroll
            for (int kb = 0; kb < 4; kb++) {
                s16x8 ak = *(const s16x8*)&Ks[(kb * 16 + l16) * 72 + kd * 32 + quad * 8];
                st[kb] = __builtin_amdgcn_mfma_f32_16x16x32_bf16(
                    ak, bq[kd], st[kb], 0, 0, 0);
            }

        // online softmax: lane owns q=l16; keys kb*16+quad*4+r, reduce over quads
        float p[4][4];
        float mx = -1e30f;
#pragma unroll
        for (int kb = 0; kb < 4; kb++)
#pragma unroll
            for (int r = 0; r < 4; r++) {
                p[kb][r] = st[kb][r] * s2;
                mx = fmaxf(mx, p[kb][r]);
            }
        mx = fmaxf(mx, __shfl_xor(mx, 16));
        mx = fmaxf(mx, __shfl_xor(mx, 32));
        float mnew = fmaxf(m_i, mx);
        float alpha = exp2f(m_i - mnew);
        float rs = 0.f;
#pragma unroll
        for (int kb = 0; kb < 4; kb++)
#pragma unroll
            for (int r = 0; r < 4; r++) {
                float pv = exp2f(p[kb][r] - mnew);
                p[kb][r] = pv; rs += pv;
            }
        rs += __shfl_xor(rs, 16);
        rs += __shfl_xor(rs, 32);
        m_i = mnew;
        l_i = l_i * alpha + rs;
#pragma unroll
        for (int dt = 0; dt < 4; dt++)
#pragma unroll
            for (int r = 0; r < 4; r++) acc_ot[dt][r] *= alpha;

        // P^T store: regs r are consecutive keys -> one b64 write per key-tile
#pragma unroll
        for (int kb = 0; kb < 4; kb++) {
            ushort4 pk;
            pk.x = f2bf(p[kb][0]); pk.y = f2bf(p[kb][1]);
            pk.z = f2bf(p[kb][2]); pk.w = f2bf(p[kb][3]);
            *(ushort4*)&Pt[w][l16 * 72 + kb * 16 + quad * 4] = pk;
        }
        __syncthreads();                 // Pt visible (and lgkm ordering)

        // O^T += V^T P^T : A = V^T frag, B = P^T frag
#pragma unroll
        for (int kk = 0; kk < 2; kk++) {
            s16x8 bp = *(const s16x8*)&Pt[w][l16 * 72 + kk * 32 + quad * 8];
#pragma unroll
            for (int dt = 0; dt < 4; dt++) {
                s16x8 av = *(const s16x8*)&Vts[(dt * 16 + l16) * 72 + kk * 32 + quad * 8];
                acc_ot[dt] = __builtin_amdgcn_mfma_f32_16x16x32_bf16(
                    av, bp, acc_ot[dt], 0, 0, 0);
            }
        }
    }

    // epilogue: lane has q=l16, dims dt*16+quad*4+r -> b64 stores
    float inv = 1.0f / l_i;
    int token = qb * 64 + w * 16 + l16;
#pragma unroll
    for (int dt = 0; dt < 4; dt++) {
        ushort4 pk;
        pk.x = f2bf(acc_ot[dt][0] * inv);
        pk.y = f2bf(acc_ot[dt][1] * inv);
        pk.z = f2bf(acc_ot[dt][2] * inv);
        pk.w = f2bf(acc_ot[dt][3] * inv);
        *(ushort4*)&o[(tokbase + token) * Dm + h * 64 + dt * 16 + quad * 4] = pk;
    }
}

// ------------------------------- launcher ----------------------------------
extern "C" void kernel_launch(void* const* d_in, const int* in_sizes, int n_in,
                              void* d_out, int out_size, void* d_ws, size_t ws_size,
                              hipStream_t stream) {
    const int M = 8192;   // B*T
    const int D = 1024, D3 = 3072, FF = 4096;

    const float* x      = (const float*)d_in[0];
    const float* ln1_g  = (const float*)d_in[1];
    const float* ln1_b  = (const float*)d_in[2];
    const float* W_ap   = (const float*)d_in[3];
    const float* b_ap   = (const float*)d_in[4];
    const float* W_qkv  = (const float*)d_in[5];
    const float* b_qkv  = (const float*)d_in[6];
    const float* W_proj = (const float*)d_in[7];
    const float* b_proj = (const float*)d_in[8];
    const float* ln2_g  = (const float*)d_in[9];
    const float* ln2_b  = (const float*)d_in[10];
    const float* W1     = (const float*)d_in[11];
    const float* b1     = (const float*)d_in[12];
    const float* W2     = (const float*)d_in[13];
    const float* b2     = (const float*)d_in[14];

    char* p = (char*)d_ws;
    auto carve = [&](size_t bytes) { char* r = p; p += (bytes + 255) & ~(size_t)255; return r; };
    u16*   WapT   = (u16*)carve((size_t)D * D * 2);
    u16*   WqkvT  = (u16*)carve((size_t)D * D3 * 2);
    u16*   WprojT = (u16*)carve((size_t)D * D * 2);
    u16*   W1T    = (u16*)carve((size_t)D * FF * 2);
    u16*   W2T    = (u16*)carve((size_t)FF * D * 2);
    u16*   aln    = (u16*)carve((size_t)M * D * 2);    // reused as gbuf
    u16*   a1     = (u16*)carve((size_t)M * D * 2);    // reused as obuf
    u16*   qkvb   = (u16*)carve((size_t)M * D3 * 2);
    float* hbuf   = (float*)carve((size_t)M * D * 4);
    u16*   f1     = (u16*)carve((size_t)M * FF * 2);
    u16* gbuf = aln;
    u16* obuf = a1;
    u16* vtg  = f1;   // V^T [b,h,dim,2048] (16MB) overlaps f1: dead before W1 GEMM

    dim3 tb(32, 8);
    transpose_f32_bf16<<<dim3(D / 32, D / 32), tb, 0, stream>>>(W_ap, WapT, D, D);
    transpose_f32_bf16<<<dim3(D3 / 32, D / 32), tb, 0, stream>>>(W_qkv, WqkvT, D, D3);
    transpose_f32_bf16<<<dim3(D / 32, D / 32), tb, 0, stream>>>(W_proj, WprojT, D, D);
    transpose_f32_bf16<<<dim3(FF / 32, D / 32), tb, 0, stream>>>(W1, W1T, D, FF);
    transpose_f32_bf16<<<dim3(D / 32, FF / 32), tb, 0, stream>>>(W2, W2T, FF, D);

    // a = LN1(x)
    ln_kernel<false><<<M, 256, 0, stream>>>(x, ln1_g, ln1_b, aln);
    // a1 = a @ W_ap + b_ap
    gemm_kernel<1, 0, 0, 0><<<dim3(D / 128, M / 128), 256, 0, stream>>>(
        aln, WapT, b_ap, nullptr, a1, nullptr, M, D, D);
    // qkv = a1 @ W_qkv + b_qkv  (V third written transposed into vtg)
    gemm_kernel<1, 0, 0, 1><<<dim3(D3 / 128, M / 128), 256, 0, stream>>>(
        a1, WqkvT, b_qkv, nullptr, qkvb, vtg, M, D3, D);
    // o = attention(qkv, vtg)
    attn_kernel<<<dim3(32, 64), 256, 0, stream>>>(qkvb, vtg, obuf);
    // h = x + o @ W_proj + b_proj   (fp32)
    gemm_kernel<0, 0, 1, 0><<<dim3(D / 128, M / 128), 256, 0, stream>>>(
        obuf, WprojT, b_proj, x, hbuf, nullptr, M, D, D);
    // g = gelu(LN2(h))
    ln_kernel<true><<<M, 256, 0, stream>>>(hbuf, ln2_g, ln2_b, gbuf);
    // f1 = gelu(g @ W1 + b1)
    gemm_kernel<1, 1, 0, 0><<<dim3(FF / 128, M / 128), 256, 0, stream>>>(
        gbuf, W1T, b1, nullptr, f1, nullptr, M, FF, D);
    // out = h + f1 @ W2 + b2   (fp32)
    gemm_kernel<0, 0, 1, 0><<<dim3(D / 128, M / 128), 256, 0, stream>>>(
        f1, W2T, b2, hbuf, (float*)d_out, nullptr, M, D, FF);
}

// Round 3
// 675.927 us; speedup vs baseline: 1.1481x; 1.0564x over previous
//
#include <hip/hip_runtime.h>
#include <hip/hip_bf16.h>
#include <math.h>

// ---------------------------------------------------------------------------
// Transformer block fwd: B=4,T=2048,D=1024,H=16,HS=64,FF=4096, fp32 in/out,
// bf16 MFMA internally. Residual path (x, h, out) kept fp32.
// R1: m97-style GEMM, S^T/O^T flash attn, V pre-transposed by qkv epilogue.
// R2: attn Q-tile 128 (K-frag reuse across 2 q-subtiles -> 2.25x fewer LDS
//     reads/MFMA), bh-fast grid for XCD L2 co-location, fmaf+exp2 softmax,
//     packed bf16 cvt, barrier 3->2, launch_bounds(256,4).
// ---------------------------------------------------------------------------

typedef unsigned short u16;
typedef __attribute__((ext_vector_type(8))) short s16x8;   // 8 x bf16 (4 VGPR)
typedef __attribute__((ext_vector_type(4))) float f32x4;   // MFMA acc

__device__ __forceinline__ u16 f2bf(float f) {
    unsigned u = __float_as_uint(f);
    u += 0x7fffu + ((u >> 16) & 1u);      // round-to-nearest-even
    return (u16)(u >> 16);
}
__device__ __forceinline__ unsigned pkbf2(float a, float b) {
    float2 t; t.x = a; t.y = b;
    __hip_bfloat162 r = __float22bfloat162_rn(t);
    return *(unsigned*)&r;
}
__device__ __forceinline__ float gelu_f(float v) {
    return 0.5f * v * (1.0f + erff(v * 0.70710678118654752f));
}
// async global->LDS, 16B per lane; lds pointer must be wave-uniform.
__device__ __forceinline__ void glds16(const u16* g, u16* l) {
    __builtin_amdgcn_global_load_lds(
        (const __attribute__((address_space(1))) void*)g,
        (__attribute__((address_space(3))) void*)l, 16, 0, 0);
}

// --------------------------- weight transpose ------------------------------
__global__ __launch_bounds__(256) void transpose_f32_bf16(
    const float* __restrict__ in, u16* __restrict__ out, int K, int N) {
    __shared__ float t[32][33];
    int n0 = blockIdx.x * 32, k0 = blockIdx.y * 32;
    int c = threadIdx.x, r0 = threadIdx.y;           // block (32,8)
#pragma unroll
    for (int i = 0; i < 4; i++) {
        int r = r0 + i * 8;
        t[r][c] = in[(size_t)(k0 + r) * N + n0 + c];
    }
    __syncthreads();
#pragma unroll
    for (int i = 0; i < 4; i++) {
        int r = r0 + i * 8;
        out[(size_t)(n0 + r) * K + k0 + c] = f2bf(t[c][r]);
    }
}

// ------------------------------ layernorm ----------------------------------
template <bool GELU>
__global__ __launch_bounds__(256) void ln_kernel(
    const float* __restrict__ x, const float* __restrict__ g,
    const float* __restrict__ bt, u16* __restrict__ out) {
    const int D = 1024;
    int row = blockIdx.x;
    float4 v = reinterpret_cast<const float4*>(x + (size_t)row * D)[threadIdx.x];
    float s = v.x + v.y + v.z + v.w;
    float s2 = v.x * v.x + v.y * v.y + v.z * v.z + v.w * v.w;
#pragma unroll
    for (int off = 32; off > 0; off >>= 1) {
        s += __shfl_down(s, off);
        s2 += __shfl_down(s2, off);
    }
    __shared__ float red[8];
    int wid = threadIdx.x >> 6;
    if ((threadIdx.x & 63) == 0) { red[wid] = s; red[wid + 4] = s2; }
    __syncthreads();
    s = red[0] + red[1] + red[2] + red[3];
    s2 = red[4] + red[5] + red[6] + red[7];
    float mu = s * (1.0f / 1024.0f);
    float var = s2 * (1.0f / 1024.0f) - mu * mu;
    float rstd = rsqrtf(var + 1e-5f);
    float4 gg = reinterpret_cast<const float4*>(g)[threadIdx.x];
    float4 bb = reinterpret_cast<const float4*>(bt)[threadIdx.x];
    float o0 = (v.x - mu) * rstd * gg.x + bb.x;
    float o1 = (v.y - mu) * rstd * gg.y + bb.y;
    float o2 = (v.z - mu) * rstd * gg.z + bb.z;
    float o3 = (v.w - mu) * rstd * gg.w + bb.w;
    if (GELU) { o0 = gelu_f(o0); o1 = gelu_f(o1); o2 = gelu_f(o2); o3 = gelu_f(o3); }
    uint2 o;
    o.x = pkbf2(o0, o1); o.y = pkbf2(o2, o3);
    reinterpret_cast<uint2*>(out + (size_t)row * D)[threadIdx.x] = o;
}

// -------------------------------- GEMM -------------------------------------
// C[M,N] = A[M,K](bf16) * BT[N,K](bf16) + bias; optional GELU / fp32 residual;
// out bf16 or fp32. 128x128 tile, BK=32, 4 waves 2x2, mfma 16x16x32.
// m97 structure: unpadded stride-32 LDS, global_load_lds width=16 staging.
// SPLIT_V: blocks with n0>=2048 (V third of qkv) write transposed to vtg.
template <int OUT_BF16, int ACT_GELU, int HAS_RES, int SPLIT_V>
__global__ __launch_bounds__(256) void gemm_kernel(
    const u16* __restrict__ A, const u16* __restrict__ BT,
    const float* __restrict__ bias, const float* __restrict__ res,
    void* __restrict__ outp, u16* __restrict__ vtg, int M, int N, int K) {
    __shared__ u16 As[128 * 32];
    __shared__ u16 Bs[128 * 32];
    const int m0 = blockIdx.y * 128, n0 = blockIdx.x * 128;
    const int tid = threadIdx.x;
    const int w = tid >> 6, lane = tid & 63, l16 = lane & 15, quad = lane >> 4;
    const int wm = (w >> 1) * 64, wn = (w & 1) * 64;

    const int srow = w * 32 + (lane >> 2);
    const int scol = (lane & 3) * 8;
    const u16* Ag = A + (size_t)(m0 + srow) * K + scol;
    const u16* Bg = BT + (size_t)(n0 + srow) * K + scol;
    u16* Asl = &As[(w * 32) * 32];     // wave-uniform LDS bases
    u16* Bsl = &Bs[(w * 32) * 32];

    f32x4 acc[4][4] = {};

    for (int k0 = 0; k0 < K; k0 += 32) {
        __syncthreads();
        glds16(Ag + k0, Asl);
        glds16(Ag + k0 + (size_t)16 * K, Asl + 16 * 32);
        glds16(Bg + k0, Bsl);
        glds16(Bg + k0 + (size_t)16 * K, Bsl + 16 * 32);
        __syncthreads();
        s16x8 af[4], bf[4];
#pragma unroll
        for (int i = 0; i < 4; i++)
            af[i] = *(const s16x8*)&As[(wm + i * 16 + l16) * 32 + quad * 8];
#pragma unroll
        for (int j = 0; j < 4; j++)
            bf[j] = *(const s16x8*)&Bs[(wn + j * 16 + l16) * 32 + quad * 8];
#pragma unroll
        for (int i = 0; i < 4; i++)
#pragma unroll
            for (int j = 0; j < 4; j++)
                acc[i][j] = __builtin_amdgcn_mfma_f32_16x16x32_bf16(
                    af[i], bf[j], acc[i][j], 0, 0, 0);
    }

    float bv[4];
#pragma unroll
    for (int j = 0; j < 4; j++) bv[j] = bias[n0 + wn + j * 16 + l16];

    if (SPLIT_V && n0 >= 2048) {
#pragma unroll
        for (int i = 0; i < 4; i++) {
            int rowb = m0 + wm + i * 16 + quad * 4;
            int bb = rowb >> 11, tt = rowb & 2047;
#pragma unroll
            for (int j = 0; j < 4; j++) {
                int vcol = n0 + wn + j * 16 + l16 - 2048;
                uint2 pk;
                pk.x = pkbf2(acc[i][j][0] + bv[j], acc[i][j][1] + bv[j]);
                pk.y = pkbf2(acc[i][j][2] + bv[j], acc[i][j][3] + bv[j]);
                *(uint2*)&vtg[((size_t)bb * 1024 + vcol) * 2048 + tt] = pk;
            }
        }
    } else {
#pragma unroll
        for (int i = 0; i < 4; i++) {
            int rowb = m0 + wm + i * 16 + quad * 4;
#pragma unroll
            for (int j = 0; j < 4; j++) {
                int col = n0 + wn + j * 16 + l16;
#pragma unroll
                for (int r = 0; r < 4; r++) {
                    float v = acc[i][j][r] + bv[j];
                    if (ACT_GELU) v = gelu_f(v);
                    size_t idx = (size_t)(rowb + r) * N + col;
                    if (HAS_RES) v += res[idx];
                    if (OUT_BF16) ((u16*)outp)[idx] = f2bf(v);
                    else          ((float*)outp)[idx] = v;
                }
            }
        }
    }
}

// ----------------------------- flash attention -----------------------------
// S^T/O^T formulation. Block = 128 q x 64-key tiles; wave owns 32 q (2
// subtiles), K/V fragments reused across subtiles. Grid (bh=64 fast, qb=16):
// all blocks of head bh land on XCD bh%8 -> K/V fetched ~once per XCD.
__global__ __launch_bounds__(256, 4) void attn_kernel(
    const u16* __restrict__ qkv, const u16* __restrict__ vtg,
    u16* __restrict__ o) {
    const int T = 2048, D3 = 3072, Dm = 1024;
    const int bh = blockIdx.x, qb = blockIdx.y;
    const int b = bh >> 4, h = bh & 15;
    const int tid = threadIdx.x;
    const int w = tid >> 6, lane = tid & 63, l16 = lane & 15, quad = lane >> 4;
    const size_t tokbase = (size_t)b * T;

    __shared__ u16 Ks[64 * 72];        // K tile [key][dim]
    __shared__ u16 Vts[64 * 72];       // V^T tile [dim][key]
    __shared__ u16 Pt[4][32 * 72];     // per-wave P as [q][key]

    // Q fragments (B operand): 2 q-subtiles x 2 k-halves
    s16x8 bq[2][2];
#pragma unroll
    for (int qs = 0; qs < 2; qs++) {
        int qrow = qb * 128 + w * 32 + qs * 16 + l16;
        const u16* qp = qkv + (tokbase + qrow) * D3 + h * 64 + quad * 8;
        bq[qs][0] = *(const s16x8*)qp;
        bq[qs][1] = *(const s16x8*)(qp + 32);
    }

    f32x4 acc_ot[2][4] = {};
    float m_i[2] = {-1e30f, -1e30f}, l_i[2] = {0.f, 0.f};
    const float s2 = 0.125f * 1.44269504088896f;   // scale * log2(e)

    const u16* kgbase = qkv + tokbase * D3 + 1024 + h * 64;
    const u16* vgbase = vtg + ((size_t)b * 1024 + h * 64) * T;

    const int srow = tid >> 3;           // 0..31 (+32 in 2nd segment)
    const int scv = (tid & 7) * 8;

    for (int kt = 0; kt < 32; kt++) {
        __syncthreads();                 // prev iter's frag reads done
#pragma unroll
        for (int s = 0; s < 2; s++) {
            int row = srow + s * 32;
            *(s16x8*)&Ks[row * 72 + scv] =
                *(const s16x8*)(kgbase + (size_t)(kt * 64 + row) * D3 + scv);
            *(s16x8*)&Vts[row * 72 + scv] =
                *(const s16x8*)(vgbase + (size_t)row * T + kt * 64 + scv);
        }
        __syncthreads();

        // S^T = K Q^T : K-fragment shared across both q-subtiles
        f32x4 st[2][4] = {};
#pragma unroll
        for (int kd = 0; kd < 2; kd++)
#pragma unroll
            for (int kb = 0; kb < 4; kb++) {
                s16x8 ak = *(const s16x8*)&Ks[(kb * 16 + l16) * 72 + kd * 32 + quad * 8];
#pragma unroll
                for (int qs = 0; qs < 2; qs++)
                    st[qs][kb] = __builtin_amdgcn_mfma_f32_16x16x32_bf16(
                        ak, bq[qs][kd], st[qs][kb], 0, 0, 0);
            }

        // online softmax per subtile; lane owns q = l16
#pragma unroll
        for (int qs = 0; qs < 2; qs++) {
            float mx = -1e30f;
#pragma unroll
            for (int kb = 0; kb < 4; kb++)
#pragma unroll
                for (int r = 0; r < 4; r++) mx = fmaxf(mx, st[qs][kb][r]);
            mx = fmaxf(mx, __shfl_xor(mx, 16));
            mx = fmaxf(mx, __shfl_xor(mx, 32));
            mx *= s2;
            float mnew = fmaxf(m_i[qs], mx);
            float alpha = exp2f(m_i[qs] - mnew);
            float rs = 0.f;
#pragma unroll
            for (int kb = 0; kb < 4; kb++)
#pragma unroll
                for (int r = 0; r < 4; r++) {
                    float pv = exp2f(fmaf(st[qs][kb][r], s2, -mnew));
                    st[qs][kb][r] = pv; rs += pv;
                }
            rs += __shfl_xor(rs, 16);
            rs += __shfl_xor(rs, 32);
            m_i[qs] = mnew;
            l_i[qs] = l_i[qs] * alpha + rs;
#pragma unroll
            for (int dt = 0; dt < 4; dt++)
#pragma unroll
                for (int r = 0; r < 4; r++) acc_ot[qs][dt][r] *= alpha;

            // P store (wave-private; same-wave DS ordering, no barrier)
#pragma unroll
            for (int kb = 0; kb < 4; kb++) {
                uint2 pk;
                pk.x = pkbf2(st[qs][kb][0], st[qs][kb][1]);
                pk.y = pkbf2(st[qs][kb][2], st[qs][kb][3]);
                *(uint2*)&Pt[w][(qs * 16 + l16) * 72 + kb * 16 + quad * 4] = pk;
            }
        }

        // O^T += V^T P^T : V-fragment shared across both q-subtiles
#pragma unroll
        for (int kk = 0; kk < 2; kk++) {
            s16x8 bp[2];
#pragma unroll
            for (int qs = 0; qs < 2; qs++)
                bp[qs] = *(const s16x8*)&Pt[w][(qs * 16 + l16) * 72 + kk * 32 + quad * 8];
#pragma unroll
            for (int dt = 0; dt < 4; dt++) {
                s16x8 av = *(const s16x8*)&Vts[(dt * 16 + l16) * 72 + kk * 32 + quad * 8];
#pragma unroll
                for (int qs = 0; qs < 2; qs++)
                    acc_ot[qs][dt] = __builtin_amdgcn_mfma_f32_16x16x32_bf16(
                        av, bp[qs], acc_ot[qs][dt], 0, 0, 0);
            }
        }
    }

    // epilogue: lane has q=l16, dims dt*16+quad*4+r -> b64 stores
#pragma unroll
    for (int qs = 0; qs < 2; qs++) {
        float inv = 1.0f / l_i[qs];
        int token = qb * 128 + w * 32 + qs * 16 + l16;
#pragma unroll
        for (int dt = 0; dt < 4; dt++) {
            uint2 pk;
            pk.x = pkbf2(acc_ot[qs][dt][0] * inv, acc_ot[qs][dt][1] * inv);
            pk.y = pkbf2(acc_ot[qs][dt][2] * inv, acc_ot[qs][dt][3] * inv);
            *(uint2*)&o[(tokbase + token) * Dm + h * 64 + dt * 16 + quad * 4] = pk;
        }
    }
}

// ------------------------------- launcher ----------------------------------
extern "C" void kernel_launch(void* const* d_in, const int* in_sizes, int n_in,
                              void* d_out, int out_size, void* d_ws, size_t ws_size,
                              hipStream_t stream) {
    const int M = 8192;   // B*T
    const int D = 1024, D3 = 3072, FF = 4096;

    const float* x      = (const float*)d_in[0];
    const float* ln1_g  = (const float*)d_in[1];
    const float* ln1_b  = (const float*)d_in[2];
    const float* W_ap   = (const float*)d_in[3];
    const float* b_ap   = (const float*)d_in[4];
    const float* W_qkv  = (const float*)d_in[5];
    const float* b_qkv  = (const float*)d_in[6];
    const float* W_proj = (const float*)d_in[7];
    const float* b_proj = (const float*)d_in[8];
    const float* ln2_g  = (const float*)d_in[9];
    const float* ln2_b  = (const float*)d_in[10];
    const float* W1     = (const float*)d_in[11];
    const float* b1     = (const float*)d_in[12];
    const float* W2     = (const float*)d_in[13];
    const float* b2     = (const float*)d_in[14];

    char* p = (char*)d_ws;
    auto carve = [&](size_t bytes) { char* r = p; p += (bytes + 255) & ~(size_t)255; return r; };
    u16*   WapT   = (u16*)carve((size_t)D * D * 2);
    u16*   WqkvT  = (u16*)carve((size_t)D * D3 * 2);
    u16*   WprojT = (u16*)carve((size_t)D * D * 2);
    u16*   W1T    = (u16*)carve((size_t)D * FF * 2);
    u16*   W2T    = (u16*)carve((size_t)FF * D * 2);
    u16*   aln    = (u16*)carve((size_t)M * D * 2);    // reused as gbuf
    u16*   a1     = (u16*)carve((size_t)M * D * 2);    // reused as obuf
    u16*   qkvb   = (u16*)carve((size_t)M * D3 * 2);
    float* hbuf   = (float*)carve((size_t)M * D * 4);
    u16*   f1     = (u16*)carve((size_t)M * FF * 2);
    u16* gbuf = aln;
    u16* obuf = a1;
    u16* vtg  = f1;   // V^T [b,h,dim,2048] (16MB) overlaps f1: dead before W1 GEMM

    dim3 tb(32, 8);
    transpose_f32_bf16<<<dim3(D / 32, D / 32), tb, 0, stream>>>(W_ap, WapT, D, D);
    transpose_f32_bf16<<<dim3(D3 / 32, D / 32), tb, 0, stream>>>(W_qkv, WqkvT, D, D3);
    transpose_f32_bf16<<<dim3(D / 32, D / 32), tb, 0, stream>>>(W_proj, WprojT, D, D);
    transpose_f32_bf16<<<dim3(FF / 32, D / 32), tb, 0, stream>>>(W1, W1T, D, FF);
    transpose_f32_bf16<<<dim3(D / 32, FF / 32), tb, 0, stream>>>(W2, W2T, FF, D);

    // a = LN1(x)
    ln_kernel<false><<<M, 256, 0, stream>>>(x, ln1_g, ln1_b, aln);
    // a1 = a @ W_ap + b_ap
    gemm_kernel<1, 0, 0, 0><<<dim3(D / 128, M / 128), 256, 0, stream>>>(
        aln, WapT, b_ap, nullptr, a1, nullptr, M, D, D);
    // qkv = a1 @ W_qkv + b_qkv  (V third written transposed into vtg)
    gemm_kernel<1, 0, 0, 1><<<dim3(D3 / 128, M / 128), 256, 0, stream>>>(
        a1, WqkvT, b_qkv, nullptr, qkvb, vtg, M, D3, D);
    // o = attention(qkv, vtg)
    attn_kernel<<<dim3(64, 16), 256, 0, stream>>>(qkvb, vtg, obuf);
    // h = x + o @ W_proj + b_proj   (fp32)
    gemm_kernel<0, 0, 1, 0><<<dim3(D / 128, M / 128), 256, 0, stream>>>(
        obuf, WprojT, b_proj, x, hbuf, nullptr, M, D, D);
    // g = gelu(LN2(h))
    ln_kernel<true><<<M, 256, 0, stream>>>(hbuf, ln2_g, ln2_b, gbuf);
    // f1 = gelu(g @ W1 + b1)
    gemm_kernel<1, 1, 0, 0><<<dim3(FF / 128, M / 128), 256, 0, stream>>>(
        gbuf, W1T, b1, nullptr, f1, nullptr, M, FF, D);
    // out = h + f1 @ W2 + b2   (fp32)
    gemm_kernel<0, 0, 1, 0><<<dim3(D / 128, M / 128), 256, 0, stream>>>(
        f1, W2T, b2, hbuf, (float*)d_out, nullptr, M, D, FF);
}

// Round 4
// 584.628 us; speedup vs baseline: 1.3274x; 1.1562x over previous
//
#include <hip/hip_runtime.h>
#include <hip/hip_bf16.h>
#include <math.h>

// ---------------------------------------------------------------------------
// Transformer block fwd: B=4,T=2048,D=1024,H=16,HS=64,FF=4096, fp32 in/out,
// bf16 MFMA internally. Residual path (x, h, out) kept fp32.
// R1: S^T/O^T flash attn, V pre-transposed by qkv epilogue.
// R2: attn Q-tile 128, bh-fast grid (XCD co-location), packed cvt.
// R3: attn bound-max softmax (m = |q|·max|k|·scale via knorm kernel) — no
//     in-loop max/alpha/rescale/shuffles, l deferred to epilogue.
//     GEMM BK=64: padded LDS stride 72 (conflict-free b128 frags), register
//     staging with next-tile loads issued before the MFMA block.
// ---------------------------------------------------------------------------

typedef unsigned short u16;
typedef __attribute__((ext_vector_type(8))) short s16x8;   // 8 x bf16 (4 VGPR)
typedef __attribute__((ext_vector_type(4))) float f32x4;   // MFMA acc

__device__ __forceinline__ u16 f2bf(float f) {
    unsigned u = __float_as_uint(f);
    u += 0x7fffu + ((u >> 16) & 1u);      // round-to-nearest-even
    return (u16)(u >> 16);
}
__device__ __forceinline__ unsigned pkbf2(float a, float b) {
    float2 t; t.x = a; t.y = b;
    __hip_bfloat162 r = __float22bfloat162_rn(t);
    return *(unsigned*)&r;
}
__device__ __forceinline__ float bf2f(short s) {
    return __uint_as_float(((unsigned)(unsigned short)s) << 16);
}
__device__ __forceinline__ float gelu_f(float v) {
    return 0.5f * v * (1.0f + erff(v * 0.70710678118654752f));
}

// --------------------------- weight transpose ------------------------------
__global__ __launch_bounds__(256) void transpose_f32_bf16(
    const float* __restrict__ in, u16* __restrict__ out, int K, int N) {
    __shared__ float t[32][33];
    int n0 = blockIdx.x * 32, k0 = blockIdx.y * 32;
    int c = threadIdx.x, r0 = threadIdx.y;           // block (32,8)
#pragma unroll
    for (int i = 0; i < 4; i++) {
        int r = r0 + i * 8;
        t[r][c] = in[(size_t)(k0 + r) * N + n0 + c];
    }
    __syncthreads();
#pragma unroll
    for (int i = 0; i < 4; i++) {
        int r = r0 + i * 8;
        out[(size_t)(n0 + r) * K + k0 + c] = f2bf(t[c][r]);
    }
}

// ------------------------------ layernorm ----------------------------------
template <bool GELU>
__global__ __launch_bounds__(256) void ln_kernel(
    const float* __restrict__ x, const float* __restrict__ g,
    const float* __restrict__ bt, u16* __restrict__ out) {
    const int D = 1024;
    int row = blockIdx.x;
    float4 v = reinterpret_cast<const float4*>(x + (size_t)row * D)[threadIdx.x];
    float s = v.x + v.y + v.z + v.w;
    float s2 = v.x * v.x + v.y * v.y + v.z * v.z + v.w * v.w;
#pragma unroll
    for (int off = 32; off > 0; off >>= 1) {
        s += __shfl_down(s, off);
        s2 += __shfl_down(s2, off);
    }
    __shared__ float red[8];
    int wid = threadIdx.x >> 6;
    if ((threadIdx.x & 63) == 0) { red[wid] = s; red[wid + 4] = s2; }
    __syncthreads();
    s = red[0] + red[1] + red[2] + red[3];
    s2 = red[4] + red[5] + red[6] + red[7];
    float mu = s * (1.0f / 1024.0f);
    float var = s2 * (1.0f / 1024.0f) - mu * mu;
    float rstd = rsqrtf(var + 1e-5f);
    float4 gg = reinterpret_cast<const float4*>(g)[threadIdx.x];
    float4 bb = reinterpret_cast<const float4*>(bt)[threadIdx.x];
    float o0 = (v.x - mu) * rstd * gg.x + bb.x;
    float o1 = (v.y - mu) * rstd * gg.y + bb.y;
    float o2 = (v.z - mu) * rstd * gg.z + bb.z;
    float o3 = (v.w - mu) * rstd * gg.w + bb.w;
    if (GELU) { o0 = gelu_f(o0); o1 = gelu_f(o1); o2 = gelu_f(o2); o3 = gelu_f(o3); }
    uint2 o;
    o.x = pkbf2(o0, o1); o.y = pkbf2(o2, o3);
    reinterpret_cast<uint2*>(out + (size_t)row * D)[threadIdx.x] = o;
}

// -------------------------------- GEMM -------------------------------------
// C[M,N] = A[M,K](bf16) * BT[N,K](bf16) + bias; optional GELU / fp32 residual;
// out bf16 or fp32. 128x128 tile, BK=64, 4 waves 2x2, mfma 16x16x32.
// LDS stride 72 (bank-conflict-free b128 frag reads); register staging with
// the next tile's global loads issued before the MFMA block so the
// pre-barrier vmcnt drain lands after compute overlapped the latency.
// SPLIT_V: blocks with n0>=2048 (V third of qkv) write transposed to vtg.
template <int OUT_BF16, int ACT_GELU, int HAS_RES, int SPLIT_V>
__global__ __launch_bounds__(256) void gemm_kernel(
    const u16* __restrict__ A, const u16* __restrict__ BT,
    const float* __restrict__ bias, const float* __restrict__ res,
    void* __restrict__ outp, u16* __restrict__ vtg, int M, int N, int K) {
    constexpr int LS = 72;
    __shared__ u16 As[128 * LS];
    __shared__ u16 Bs[128 * LS];
    const int m0 = blockIdx.y * 128, n0 = blockIdx.x * 128;
    const int tid = threadIdx.x;
    const int w = tid >> 6, lane = tid & 63, l16 = lane & 15, quad = lane >> 4;
    const int wm = (w >> 1) * 64, wn = (w & 1) * 64;

    // staging map: element e = c*256 + tid -> row e>>3 (0..127), col (e&7)*8
    const int r0 = tid >> 3;
    const int scol = (tid & 7) * 8;
    const u16* Ag = A + (size_t)(m0 + r0) * K + scol;
    const u16* Bg = BT + (size_t)(n0 + r0) * K + scol;

    s16x8 ra[4], rb[4];
#pragma unroll
    for (int c = 0; c < 4; c++) {
        ra[c] = *(const s16x8*)(Ag + (size_t)(c * 32) * K);
        rb[c] = *(const s16x8*)(Bg + (size_t)(c * 32) * K);
    }

    f32x4 acc[4][4] = {};

    for (int k0 = 0; k0 < K; k0 += 64) {
        __syncthreads();                       // prev frag reads done
#pragma unroll
        for (int c = 0; c < 4; c++) {
            *(s16x8*)&As[(c * 32 + r0) * LS + scol] = ra[c];
            *(s16x8*)&Bs[(c * 32 + r0) * LS + scol] = rb[c];
        }
        __syncthreads();                       // staging visible
        if (k0 + 64 < K) {
#pragma unroll
            for (int c = 0; c < 4; c++) {      // issue next tile early
                ra[c] = *(const s16x8*)(Ag + (size_t)(c * 32) * K + k0 + 64);
                rb[c] = *(const s16x8*)(Bg + (size_t)(c * 32) * K + k0 + 64);
            }
        }
#pragma unroll
        for (int kd = 0; kd < 2; kd++) {
            s16x8 af[4], bf[4];
#pragma unroll
            for (int i = 0; i < 4; i++)
                af[i] = *(const s16x8*)&As[(wm + i * 16 + l16) * LS + kd * 32 + quad * 8];
#pragma unroll
            for (int j = 0; j < 4; j++)
                bf[j] = *(const s16x8*)&Bs[(wn + j * 16 + l16) * LS + kd * 32 + quad * 8];
#pragma unroll
            for (int i = 0; i < 4; i++)
#pragma unroll
                for (int j = 0; j < 4; j++)
                    acc[i][j] = __builtin_amdgcn_mfma_f32_16x16x32_bf16(
                        af[i], bf[j], acc[i][j], 0, 0, 0);
        }
    }

    float bv[4];
#pragma unroll
    for (int j = 0; j < 4; j++) bv[j] = bias[n0 + wn + j * 16 + l16];

    if (SPLIT_V && n0 >= 2048) {
#pragma unroll
        for (int i = 0; i < 4; i++) {
            int rowb = m0 + wm + i * 16 + quad * 4;
            int bb = rowb >> 11, tt = rowb & 2047;
#pragma unroll
            for (int j = 0; j < 4; j++) {
                int vcol = n0 + wn + j * 16 + l16 - 2048;
                uint2 pk;
                pk.x = pkbf2(acc[i][j][0] + bv[j], acc[i][j][1] + bv[j]);
                pk.y = pkbf2(acc[i][j][2] + bv[j], acc[i][j][3] + bv[j]);
                *(uint2*)&vtg[((size_t)bb * 1024 + vcol) * 2048 + tt] = pk;
            }
        }
    } else {
#pragma unroll
        for (int i = 0; i < 4; i++) {
            int rowb = m0 + wm + i * 16 + quad * 4;
#pragma unroll
            for (int j = 0; j < 4; j++) {
                int col = n0 + wn + j * 16 + l16;
#pragma unroll
                for (int r = 0; r < 4; r++) {
                    float v = acc[i][j][r] + bv[j];
                    if (ACT_GELU) v = gelu_f(v);
                    size_t idx = (size_t)(rowb + r) * N + col;
                    if (HAS_RES) v += res[idx];
                    if (OUT_BF16) ((u16*)outp)[idx] = f2bf(v);
                    else          ((float*)outp)[idx] = v;
                }
            }
        }
    }
}

// ------------------------------ K norms ------------------------------------
// maxkn[bh] = max over t of ||k[b,t,h,:]||  (from bf16 K exactly as MFMA sees it)
__global__ __launch_bounds__(256) void knorm_kernel(
    const u16* __restrict__ qkv, float* __restrict__ maxkn) {
    const int T = 2048, D3 = 3072;
    int bh = blockIdx.x, b = bh >> 4, h = bh & 15;
    const u16* kg = qkv + (size_t)b * T * D3 + 1024 + h * 64;
    float mx = 0.f;
#pragma unroll
    for (int i = 0; i < 8; i++) {
        const u16* kp = kg + (size_t)(threadIdx.x + i * 256) * D3;
        float ss = 0.f;
#pragma unroll
        for (int c = 0; c < 8; c++) {
            s16x8 v = *(const s16x8*)(kp + c * 8);
#pragma unroll
            for (int j = 0; j < 8; j++) { float f = bf2f(v[j]); ss = fmaf(f, f, ss); }
        }
        mx = fmaxf(mx, ss);
    }
#pragma unroll
    for (int off = 32; off > 0; off >>= 1) mx = fmaxf(mx, __shfl_down(mx, off));
    __shared__ float red[4];
    if ((threadIdx.x & 63) == 0) red[threadIdx.x >> 6] = mx;
    __syncthreads();
    if (threadIdx.x == 0)
        maxkn[bh] = sqrtf(fmaxf(fmaxf(red[0], red[1]), fmaxf(red[2], red[3])));
}

// ----------------------------- flash attention -----------------------------
// S^T/O^T formulation, 128 q/block, bound-max softmax:
// m2 = |q|*max|k|*scale*log2e (Cauchy-Schwarz upper bound on the scaled score)
// -> p = exp2(s*s2 - m2) needs no running max, no alpha, no rescale; l is a
// plain per-lane sum reduced across quads once at the end.
__global__ __launch_bounds__(256, 4) void attn_kernel(
    const u16* __restrict__ qkv, const u16* __restrict__ vtg,
    const float* __restrict__ maxkn, u16* __restrict__ o) {
    const int T = 2048, D3 = 3072, Dm = 1024;
    const int bh = blockIdx.x, qb = blockIdx.y;
    const int b = bh >> 4, h = bh & 15;
    const int tid = threadIdx.x;
    const int w = tid >> 6, lane = tid & 63, l16 = lane & 15, quad = lane >> 4;
    const size_t tokbase = (size_t)b * T;
    const float s2 = 0.125f * 1.44269504088896f;   // scale * log2(e)

    __shared__ u16 Ks[64 * 72];        // K tile [key][dim]
    __shared__ u16 Vts[64 * 72];       // V^T tile [dim][key]
    __shared__ u16 Pt[4][32 * 72];     // per-wave P as [q][key]

    // Q fragments (B operand) + per-row |q| -> m2 bound
    s16x8 bq[2][2];
    float m2[2];
    const float kn = maxkn[bh];
#pragma unroll
    for (int qs = 0; qs < 2; qs++) {
        int qrow = qb * 128 + w * 32 + qs * 16 + l16;
        const u16* qp = qkv + (tokbase + qrow) * D3 + h * 64 + quad * 8;
        bq[qs][0] = *(const s16x8*)qp;
        bq[qs][1] = *(const s16x8*)(qp + 32);
        float ss = 0.f;
#pragma unroll
        for (int kd = 0; kd < 2; kd++)
#pragma unroll
            for (int j = 0; j < 8; j++) {
                float v = bf2f(bq[qs][kd][j]); ss = fmaf(v, v, ss);
            }
        ss += __shfl_xor(ss, 16);
        ss += __shfl_xor(ss, 32);
        m2[qs] = sqrtf(ss) * kn * s2;
    }

    f32x4 acc_ot[2][4] = {};
    float lp[2] = {0.f, 0.f};

    const u16* kgbase = qkv + tokbase * D3 + 1024 + h * 64;
    const u16* vgbase = vtg + ((size_t)b * 1024 + h * 64) * T;

    const int srow = tid >> 3;           // 0..31 (+32 in 2nd segment)
    const int scv = (tid & 7) * 8;

    for (int kt = 0; kt < 32; kt++) {
        __syncthreads();                 // prev iter's frag reads done
#pragma unroll
        for (int s = 0; s < 2; s++) {
            int row = srow + s * 32;
            *(s16x8*)&Ks[row * 72 + scv] =
                *(const s16x8*)(kgbase + (size_t)(kt * 64 + row) * D3 + scv);
            *(s16x8*)&Vts[row * 72 + scv] =
                *(const s16x8*)(vgbase + (size_t)row * T + kt * 64 + scv);
        }
        __syncthreads();

        // S^T = K Q^T : K-fragment shared across both q-subtiles
        f32x4 st[2][4] = {};
#pragma unroll
        for (int kd = 0; kd < 2; kd++)
#pragma unroll
            for (int kb = 0; kb < 4; kb++) {
                s16x8 ak = *(const s16x8*)&Ks[(kb * 16 + l16) * 72 + kd * 32 + quad * 8];
#pragma unroll
                for (int qs = 0; qs < 2; qs++)
                    st[qs][kb] = __builtin_amdgcn_mfma_f32_16x16x32_bf16(
                        ak, bq[qs][kd], st[qs][kb], 0, 0, 0);
            }

        // p = exp2(s*s2 - m2); deferred l; pack to Pt (wave-private, no barrier)
#pragma unroll
        for (int qs = 0; qs < 2; qs++) {
            float acc_l = 0.f;
#pragma unroll
            for (int kb = 0; kb < 4; kb++) {
#pragma unroll
                for (int r = 0; r < 4; r++) {
                    float pv = __builtin_amdgcn_exp2f(fmaf(st[qs][kb][r], s2, -m2[qs]));
                    st[qs][kb][r] = pv;
                    acc_l += pv;
                }
                uint2 pk;
                pk.x = pkbf2(st[qs][kb][0], st[qs][kb][1]);
                pk.y = pkbf2(st[qs][kb][2], st[qs][kb][3]);
                *(uint2*)&Pt[w][(qs * 16 + l16) * 72 + kb * 16 + quad * 4] = pk;
            }
            lp[qs] += acc_l;
        }

        // O^T += V^T P^T : V-fragment shared across both q-subtiles
#pragma unroll
        for (int kk = 0; kk < 2; kk++) {
            s16x8 bp[2];
#pragma unroll
            for (int qs = 0; qs < 2; qs++)
                bp[qs] = *(const s16x8*)&Pt[w][(qs * 16 + l16) * 72 + kk * 32 + quad * 8];
#pragma unroll
            for (int dt = 0; dt < 4; dt++) {
                s16x8 av = *(const s16x8*)&Vts[(dt * 16 + l16) * 72 + kk * 32 + quad * 8];
#pragma unroll
                for (int qs = 0; qs < 2; qs++)
                    acc_ot[qs][dt] = __builtin_amdgcn_mfma_f32_16x16x32_bf16(
                        av, bp[qs], acc_ot[qs][dt], 0, 0, 0);
            }
        }
    }

    // epilogue: reduce l across quads, normalize, b64 stores
#pragma unroll
    for (int qs = 0; qs < 2; qs++) {
        float l = lp[qs];
        l += __shfl_xor(l, 16);
        l += __shfl_xor(l, 32);
        float inv = 1.0f / l;
        int token = qb * 128 + w * 32 + qs * 16 + l16;
#pragma unroll
        for (int dt = 0; dt < 4; dt++) {
            uint2 pk;
            pk.x = pkbf2(acc_ot[qs][dt][0] * inv, acc_ot[qs][dt][1] * inv);
            pk.y = pkbf2(acc_ot[qs][dt][2] * inv, acc_ot[qs][dt][3] * inv);
            *(uint2*)&o[(tokbase + token) * Dm + h * 64 + dt * 16 + quad * 4] = pk;
        }
    }
}

// ------------------------------- launcher ----------------------------------
extern "C" void kernel_launch(void* const* d_in, const int* in_sizes, int n_in,
                              void* d_out, int out_size, void* d_ws, size_t ws_size,
                              hipStream_t stream) {
    const int M = 8192;   // B*T
    const int D = 1024, D3 = 3072, FF = 4096;

    const float* x      = (const float*)d_in[0];
    const float* ln1_g  = (const float*)d_in[1];
    const float* ln1_b  = (const float*)d_in[2];
    const float* W_ap   = (const float*)d_in[3];
    const float* b_ap   = (const float*)d_in[4];
    const float* W_qkv  = (const float*)d_in[5];
    const float* b_qkv  = (const float*)d_in[6];
    const float* W_proj = (const float*)d_in[7];
    const float* b_proj = (const float*)d_in[8];
    const float* ln2_g  = (const float*)d_in[9];
    const float* ln2_b  = (const float*)d_in[10];
    const float* W1     = (const float*)d_in[11];
    const float* b1     = (const float*)d_in[12];
    const float* W2     = (const float*)d_in[13];
    const float* b2     = (const float*)d_in[14];

    char* p = (char*)d_ws;
    auto carve = [&](size_t bytes) { char* r = p; p += (bytes + 255) & ~(size_t)255; return r; };
    u16*   WapT   = (u16*)carve((size_t)D * D * 2);
    u16*   WqkvT  = (u16*)carve((size_t)D * D3 * 2);
    u16*   WprojT = (u16*)carve((size_t)D * D * 2);
    u16*   W1T    = (u16*)carve((size_t)D * FF * 2);
    u16*   W2T    = (u16*)carve((size_t)FF * D * 2);
    u16*   aln    = (u16*)carve((size_t)M * D * 2);    // reused as gbuf
    u16*   a1     = (u16*)carve((size_t)M * D * 2);    // reused as obuf
    u16*   qkvb   = (u16*)carve((size_t)M * D3 * 2);
    float* hbuf   = (float*)carve((size_t)M * D * 4);
    u16*   f1     = (u16*)carve((size_t)M * FF * 2);
    float* maxkn  = (float*)carve(64 * 4);
    u16* gbuf = aln;
    u16* obuf = a1;
    u16* vtg  = f1;   // V^T [b,h,dim,2048] (16MB) overlaps f1: dead before W1 GEMM

    dim3 tb(32, 8);
    transpose_f32_bf16<<<dim3(D / 32, D / 32), tb, 0, stream>>>(W_ap, WapT, D, D);
    transpose_f32_bf16<<<dim3(D3 / 32, D / 32), tb, 0, stream>>>(W_qkv, WqkvT, D, D3);
    transpose_f32_bf16<<<dim3(D / 32, D / 32), tb, 0, stream>>>(W_proj, WprojT, D, D);
    transpose_f32_bf16<<<dim3(FF / 32, D / 32), tb, 0, stream>>>(W1, W1T, D, FF);
    transpose_f32_bf16<<<dim3(D / 32, FF / 32), tb, 0, stream>>>(W2, W2T, FF, D);

    // a = LN1(x)
    ln_kernel<false><<<M, 256, 0, stream>>>(x, ln1_g, ln1_b, aln);
    // a1 = a @ W_ap + b_ap
    gemm_kernel<1, 0, 0, 0><<<dim3(D / 128, M / 128), 256, 0, stream>>>(
        aln, WapT, b_ap, nullptr, a1, nullptr, M, D, D);
    // qkv = a1 @ W_qkv + b_qkv  (V third written transposed into vtg)
    gemm_kernel<1, 0, 0, 1><<<dim3(D3 / 128, M / 128), 256, 0, stream>>>(
        a1, WqkvT, b_qkv, nullptr, qkvb, vtg, M, D3, D);
    // per-(b,h) max K-norm for the softmax bound
    knorm_kernel<<<64, 256, 0, stream>>>(qkvb, maxkn);
    // o = attention(qkv, vtg)
    attn_kernel<<<dim3(64, 16), 256, 0, stream>>>(qkvb, vtg, maxkn, obuf);
    // h = x + o @ W_proj + b_proj   (fp32)
    gemm_kernel<0, 0, 1, 0><<<dim3(D / 128, M / 128), 256, 0, stream>>>(
        obuf, WprojT, b_proj, x, hbuf, nullptr, M, D, D);
    // g = gelu(LN2(h))
    ln_kernel<true><<<M, 256, 0, stream>>>(hbuf, ln2_g, ln2_b, gbuf);
    // f1 = gelu(g @ W1 + b1)
    gemm_kernel<1, 1, 0, 0><<<dim3(FF / 128, M / 128), 256, 0, stream>>>(
        gbuf, W1T, b1, nullptr, f1, nullptr, M, FF, D);
    // out = h + f1 @ W2 + b2   (fp32)
    gemm_kernel<0, 0, 1, 0><<<dim3(D / 128, M / 128), 256, 0, stream>>>(
        f1, W2T, b2, hbuf, (float*)d_out, nullptr, M, D, FF);
}

// Round 5
// 571.108 us; speedup vs baseline: 1.3588x; 1.0237x over previous
//
#include <hip/hip_runtime.h>
#include <hip/hip_bf16.h>
#include <math.h>

// ---------------------------------------------------------------------------
// Transformer block fwd: B=4,T=2048,D=1024,H=16,HS=64,FF=4096, fp32 in/out,
// bf16 MFMA internally. Residual path (x, h, out) kept fp32.
// R1: S^T/O^T flash attn, V pre-transposed by qkv epilogue.
// R2: attn Q-tile 128, bh-fast grid (XCD co-location), packed cvt.
// R3: attn bound-max softmax (m = |q|·max|k|·scale); GEMM BK=64.
// R4: GEMM glds16 staging with XOR-swizzled stride-64 LDS (conflict-free
//     b128 frag reads, no staging VGPRs/ds_writes); tanh-form fast GELU
//     (exp2+rcp, overflow-safe) replacing erff in GEMM epilogue and LN.
// ---------------------------------------------------------------------------

typedef unsigned short u16;
typedef __attribute__((ext_vector_type(8))) short s16x8;   // 8 x bf16 (4 VGPR)
typedef __attribute__((ext_vector_type(4))) float f32x4;   // MFMA acc

__device__ __forceinline__ u16 f2bf(float f) {
    unsigned u = __float_as_uint(f);
    u += 0x7fffu + ((u >> 16) & 1u);      // round-to-nearest-even
    return (u16)(u >> 16);
}
__device__ __forceinline__ unsigned pkbf2(float a, float b) {
    float2 t; t.x = a; t.y = b;
    __hip_bfloat162 r = __float22bfloat162_rn(t);
    return *(unsigned*)&r;
}
__device__ __forceinline__ float bf2f(short s) {
    return __uint_as_float(((unsigned)(unsigned short)s) << 16);
}
// tanh-form GELU via hw exp2 + rcp (~10 VALU). |err| vs exact erf-GELU
// <= ~3e-3, far under the bf16 quantization already in the pipeline.
// th = 1 - 2/(e^{2x}+1) is overflow-safe (t=inf -> th=1, t=0 -> th=-1).
__device__ __forceinline__ float gelu_f(float v) {
    float u = v * v;
    float x = v * fmaf(0.0356774081f, u, 0.7978845608f);
    float t = __builtin_amdgcn_exp2f(x * 2.885390082f);    // e^{2x}
    float th = fmaf(-2.0f, __builtin_amdgcn_rcpf(t + 1.0f), 1.0f);
    float hv = 0.5f * v;
    return fmaf(hv, th, hv);
}
// async global->LDS, 16B per lane; lds pointer must be wave-uniform.
__device__ __forceinline__ void glds16(const u16* g, u16* l) {
    __builtin_amdgcn_global_load_lds(
        (const __attribute__((address_space(1))) void*)g,
        (__attribute__((address_space(3))) void*)l, 16, 0, 0);
}

// --------------------------- weight transpose ------------------------------
__global__ __launch_bounds__(256) void transpose_f32_bf16(
    const float* __restrict__ in, u16* __restrict__ out, int K, int N) {
    __shared__ float t[32][33];
    int n0 = blockIdx.x * 32, k0 = blockIdx.y * 32;
    int c = threadIdx.x, r0 = threadIdx.y;           // block (32,8)
#pragma unroll
    for (int i = 0; i < 4; i++) {
        int r = r0 + i * 8;
        t[r][c] = in[(size_t)(k0 + r) * N + n0 + c];
    }
    __syncthreads();
#pragma unroll
    for (int i = 0; i < 4; i++) {
        int r = r0 + i * 8;
        out[(size_t)(n0 + r) * K + k0 + c] = f2bf(t[c][r]);
    }
}

// ------------------------------ layernorm ----------------------------------
template <bool GELU>
__global__ __launch_bounds__(256) void ln_kernel(
    const float* __restrict__ x, const float* __restrict__ g,
    const float* __restrict__ bt, u16* __restrict__ out) {
    const int D = 1024;
    int row = blockIdx.x;
    float4 v = reinterpret_cast<const float4*>(x + (size_t)row * D)[threadIdx.x];
    float s = v.x + v.y + v.z + v.w;
    float s2 = v.x * v.x + v.y * v.y + v.z * v.z + v.w * v.w;
#pragma unroll
    for (int off = 32; off > 0; off >>= 1) {
        s += __shfl_down(s, off);
        s2 += __shfl_down(s2, off);
    }
    __shared__ float red[8];
    int wid = threadIdx.x >> 6;
    if ((threadIdx.x & 63) == 0) { red[wid] = s; red[wid + 4] = s2; }
    __syncthreads();
    s = red[0] + red[1] + red[2] + red[3];
    s2 = red[4] + red[5] + red[6] + red[7];
    float mu = s * (1.0f / 1024.0f);
    float var = s2 * (1.0f / 1024.0f) - mu * mu;
    float rstd = rsqrtf(var + 1e-5f);
    float4 gg = reinterpret_cast<const float4*>(g)[threadIdx.x];
    float4 bb = reinterpret_cast<const float4*>(bt)[threadIdx.x];
    float o0 = (v.x - mu) * rstd * gg.x + bb.x;
    float o1 = (v.y - mu) * rstd * gg.y + bb.y;
    float o2 = (v.z - mu) * rstd * gg.z + bb.z;
    float o3 = (v.w - mu) * rstd * gg.w + bb.w;
    if (GELU) { o0 = gelu_f(o0); o1 = gelu_f(o1); o2 = gelu_f(o2); o3 = gelu_f(o3); }
    uint2 o;
    o.x = pkbf2(o0, o1); o.y = pkbf2(o2, o3);
    reinterpret_cast<uint2*>(out + (size_t)row * D)[threadIdx.x] = o;
}

// -------------------------------- GEMM -------------------------------------
// C[M,N] = A[M,K](bf16) * BT[N,K](bf16) + bias; optional GELU / fp32 residual;
// out bf16 or fp32. 128x128 tile, BK=64, 4 waves 2x2, mfma 16x16x32.
// Staging: glds16 (DMA, no VGPR round-trip). Lane l fetches global col-group
// (l&7)^(l>>3), so LDS slot [r][s] holds col-group s^(r&7): frag b128 reads at
// ((G=kd*4+quad)^(row&7))*16B are bank-conflict-free on an unpadded stride-64
// layout (glds16 forbids padding: dest is base + lane*16).
// SPLIT_V: blocks with n0>=2048 (V third of qkv) write transposed to vtg.
template <int OUT_BF16, int ACT_GELU, int HAS_RES, int SPLIT_V>
__global__ __launch_bounds__(256) void gemm_kernel(
    const u16* __restrict__ A, const u16* __restrict__ BT,
    const float* __restrict__ bias, const float* __restrict__ res,
    void* __restrict__ outp, u16* __restrict__ vtg, int M, int N, int K) {
    __shared__ u16 As[128 * 64];
    __shared__ u16 Bs[128 * 64];
    const int m0 = blockIdx.y * 128, n0 = blockIdx.x * 128;
    const int tid = threadIdx.x;
    const int w = tid >> 6, lane = tid & 63, l16 = lane & 15, quad = lane >> 4;
    const int wm = (w >> 1) * 64, wn = (w & 1) * 64;

    // wave w stages rows [w*32, w*32+32); each glds16 covers 8 rows x 64 cols.
    const int lrow = lane >> 3;                    // row within 8-row group
    const int lcol = ((lane & 7) ^ lrow) * 8;      // XOR-swizzled col group
    const u16* Ag = A + (size_t)(m0 + w * 32 + lrow) * K + lcol;
    const u16* Bg = BT + (size_t)(n0 + w * 32 + lrow) * K + lcol;
    u16* Asl = &As[(w * 32) * 64];                 // wave-uniform LDS bases
    u16* Bsl = &Bs[(w * 32) * 64];

    f32x4 acc[4][4] = {};

    for (int k0 = 0; k0 < K; k0 += 64) {
        __syncthreads();                           // prev frag reads done
#pragma unroll
        for (int j = 0; j < 4; j++) {
            glds16(Ag + k0 + (size_t)(j * 8) * K, Asl + j * 8 * 64);
            glds16(Bg + k0 + (size_t)(j * 8) * K, Bsl + j * 8 * 64);
        }
        __syncthreads();                           // vmcnt drain: staging visible
#pragma unroll
        for (int kd = 0; kd < 2; kd++) {
            s16x8 af[4], bf[4];
#pragma unroll
            for (int i = 0; i < 4; i++) {
                int r = wm + i * 16 + l16;
                af[i] = *(const s16x8*)&As[r * 64 + ((kd * 4 + quad) ^ (lane & 7)) * 8];
            }
#pragma unroll
            for (int j = 0; j < 4; j++) {
                int r = wn + j * 16 + l16;
                bf[j] = *(const s16x8*)&Bs[r * 64 + ((kd * 4 + quad) ^ (lane & 7)) * 8];
            }
#pragma unroll
            for (int i = 0; i < 4; i++)
#pragma unroll
                for (int j = 0; j < 4; j++)
                    acc[i][j] = __builtin_amdgcn_mfma_f32_16x16x32_bf16(
                        af[i], bf[j], acc[i][j], 0, 0, 0);
        }
    }

    float bv[4];
#pragma unroll
    for (int j = 0; j < 4; j++) bv[j] = bias[n0 + wn + j * 16 + l16];

    if (SPLIT_V && n0 >= 2048) {
#pragma unroll
        for (int i = 0; i < 4; i++) {
            int rowb = m0 + wm + i * 16 + quad * 4;
            int bb = rowb >> 11, tt = rowb & 2047;
#pragma unroll
            for (int j = 0; j < 4; j++) {
                int vcol = n0 + wn + j * 16 + l16 - 2048;
                uint2 pk;
                pk.x = pkbf2(acc[i][j][0] + bv[j], acc[i][j][1] + bv[j]);
                pk.y = pkbf2(acc[i][j][2] + bv[j], acc[i][j][3] + bv[j]);
                *(uint2*)&vtg[((size_t)bb * 1024 + vcol) * 2048 + tt] = pk;
            }
        }
    } else {
#pragma unroll
        for (int i = 0; i < 4; i++) {
            int rowb = m0 + wm + i * 16 + quad * 4;
#pragma unroll
            for (int j = 0; j < 4; j++) {
                int col = n0 + wn + j * 16 + l16;
#pragma unroll
                for (int r = 0; r < 4; r++) {
                    float v = acc[i][j][r] + bv[j];
                    if (ACT_GELU) v = gelu_f(v);
                    size_t idx = (size_t)(rowb + r) * N + col;
                    if (HAS_RES) v += res[idx];
                    if (OUT_BF16) ((u16*)outp)[idx] = f2bf(v);
                    else          ((float*)outp)[idx] = v;
                }
            }
        }
    }
}

// ------------------------------ K norms ------------------------------------
// maxkn[bh] = max over t of ||k[b,t,h,:]||  (from bf16 K exactly as MFMA sees it)
__global__ __launch_bounds__(256) void knorm_kernel(
    const u16* __restrict__ qkv, float* __restrict__ maxkn) {
    const int T = 2048, D3 = 3072;
    int bh = blockIdx.x, b = bh >> 4, h = bh & 15;
    const u16* kg = qkv + (size_t)b * T * D3 + 1024 + h * 64;
    float mx = 0.f;
#pragma unroll
    for (int i = 0; i < 8; i++) {
        const u16* kp = kg + (size_t)(threadIdx.x + i * 256) * D3;
        float ss = 0.f;
#pragma unroll
        for (int c = 0; c < 8; c++) {
            s16x8 v = *(const s16x8*)(kp + c * 8);
#pragma unroll
            for (int j = 0; j < 8; j++) { float f = bf2f(v[j]); ss = fmaf(f, f, ss); }
        }
        mx = fmaxf(mx, ss);
    }
#pragma unroll
    for (int off = 32; off > 0; off >>= 1) mx = fmaxf(mx, __shfl_down(mx, off));
    __shared__ float red[4];
    if ((threadIdx.x & 63) == 0) red[threadIdx.x >> 6] = mx;
    __syncthreads();
    if (threadIdx.x == 0)
        maxkn[bh] = sqrtf(fmaxf(fmaxf(red[0], red[1]), fmaxf(red[2], red[3])));
}

// ----------------------------- flash attention -----------------------------
// S^T/O^T formulation, 128 q/block, bound-max softmax:
// m2 = |q|*max|k|*scale*log2e (Cauchy-Schwarz upper bound on the scaled score)
// -> p = exp2(s*s2 - m2) needs no running max, no alpha, no rescale; l is a
// plain per-lane sum reduced across quads once at the end.
__global__ __launch_bounds__(256, 4) void attn_kernel(
    const u16* __restrict__ qkv, const u16* __restrict__ vtg,
    const float* __restrict__ maxkn, u16* __restrict__ o) {
    const int T = 2048, D3 = 3072, Dm = 1024;
    const int bh = blockIdx.x, qb = blockIdx.y;
    const int b = bh >> 4, h = bh & 15;
    const int tid = threadIdx.x;
    const int w = tid >> 6, lane = tid & 63, l16 = lane & 15, quad = lane >> 4;
    const size_t tokbase = (size_t)b * T;
    const float s2 = 0.125f * 1.44269504088896f;   // scale * log2(e)

    __shared__ u16 Ks[64 * 72];        // K tile [key][dim]
    __shared__ u16 Vts[64 * 72];       // V^T tile [dim][key]
    __shared__ u16 Pt[4][32 * 72];     // per-wave P as [q][key]

    // Q fragments (B operand) + per-row |q| -> m2 bound
    s16x8 bq[2][2];
    float m2[2];
    const float kn = maxkn[bh];
#pragma unroll
    for (int qs = 0; qs < 2; qs++) {
        int qrow = qb * 128 + w * 32 + qs * 16 + l16;
        const u16* qp = qkv + (tokbase + qrow) * D3 + h * 64 + quad * 8;
        bq[qs][0] = *(const s16x8*)qp;
        bq[qs][1] = *(const s16x8*)(qp + 32);
        float ss = 0.f;
#pragma unroll
        for (int kd = 0; kd < 2; kd++)
#pragma unroll
            for (int j = 0; j < 8; j++) {
                float v = bf2f(bq[qs][kd][j]); ss = fmaf(v, v, ss);
            }
        ss += __shfl_xor(ss, 16);
        ss += __shfl_xor(ss, 32);
        m2[qs] = sqrtf(ss) * kn * s2;
    }

    f32x4 acc_ot[2][4] = {};
    float lp[2] = {0.f, 0.f};

    const u16* kgbase = qkv + tokbase * D3 + 1024 + h * 64;
    const u16* vgbase = vtg + ((size_t)b * 1024 + h * 64) * T;

    const int srow = tid >> 3;           // 0..31 (+32 in 2nd segment)
    const int scv = (tid & 7) * 8;

    for (int kt = 0; kt < 32; kt++) {
        __syncthreads();                 // prev iter's frag reads done
#pragma unroll
        for (int s = 0; s < 2; s++) {
            int row = srow + s * 32;
            *(s16x8*)&Ks[row * 72 + scv] =
                *(const s16x8*)(kgbase + (size_t)(kt * 64 + row) * D3 + scv);
            *(s16x8*)&Vts[row * 72 + scv] =
                *(const s16x8*)(vgbase + (size_t)row * T + kt * 64 + scv);
        }
        __syncthreads();

        // S^T = K Q^T : K-fragment shared across both q-subtiles
        f32x4 st[2][4] = {};
#pragma unroll
        for (int kd = 0; kd < 2; kd++)
#pragma unroll
            for (int kb = 0; kb < 4; kb++) {
                s16x8 ak = *(const s16x8*)&Ks[(kb * 16 + l16) * 72 + kd * 32 + quad * 8];
#pragma unroll
                for (int qs = 0; qs < 2; qs++)
                    st[qs][kb] = __builtin_amdgcn_mfma_f32_16x16x32_bf16(
                        ak, bq[qs][kd], st[qs][kb], 0, 0, 0);
            }

        // p = exp2(s*s2 - m2); deferred l; pack to Pt (wave-private, no barrier)
#pragma unroll
        for (int qs = 0; qs < 2; qs++) {
            float acc_l = 0.f;
#pragma unroll
            for (int kb = 0; kb < 4; kb++) {
#pragma unroll
                for (int r = 0; r < 4; r++) {
                    float pv = __builtin_amdgcn_exp2f(fmaf(st[qs][kb][r], s2, -m2[qs]));
                    st[qs][kb][r] = pv;
                    acc_l += pv;
                }
                uint2 pk;
                pk.x = pkbf2(st[qs][kb][0], st[qs][kb][1]);
                pk.y = pkbf2(st[qs][kb][2], st[qs][kb][3]);
                *(uint2*)&Pt[w][(qs * 16 + l16) * 72 + kb * 16 + quad * 4] = pk;
            }
            lp[qs] += acc_l;
        }

        // O^T += V^T P^T : V-fragment shared across both q-subtiles
#pragma unroll
        for (int kk = 0; kk < 2; kk++) {
            s16x8 bp[2];
#pragma unroll
            for (int qs = 0; qs < 2; qs++)
                bp[qs] = *(const s16x8*)&Pt[w][(qs * 16 + l16) * 72 + kk * 32 + quad * 8];
#pragma unroll
            for (int dt = 0; dt < 4; dt++) {
                s16x8 av = *(const s16x8*)&Vts[(dt * 16 + l16) * 72 + kk * 32 + quad * 8];
#pragma unroll
                for (int qs = 0; qs < 2; qs++)
                    acc_ot[qs][dt] = __builtin_amdgcn_mfma_f32_16x16x32_bf16(
                        av, bp[qs], acc_ot[qs][dt], 0, 0, 0);
            }
        }
    }

    // epilogue: reduce l across quads, normalize, b64 stores
#pragma unroll
    for (int qs = 0; qs < 2; qs++) {
        float l = lp[qs];
        l += __shfl_xor(l, 16);
        l += __shfl_xor(l, 32);
        float inv = 1.0f / l;
        int token = qb * 128 + w * 32 + qs * 16 + l16;
#pragma unroll
        for (int dt = 0; dt < 4; dt++) {
            uint2 pk;
            pk.x = pkbf2(acc_ot[qs][dt][0] * inv, acc_ot[qs][dt][1] * inv);
            pk.y = pkbf2(acc_ot[qs][dt][2] * inv, acc_ot[qs][dt][3] * inv);
            *(uint2*)&o[(tokbase + token) * Dm + h * 64 + dt * 16 + quad * 4] = pk;
        }
    }
}

// ------------------------------- launcher ----------------------------------
extern "C" void kernel_launch(void* const* d_in, const int* in_sizes, int n_in,
                              void* d_out, int out_size, void* d_ws, size_t ws_size,
                              hipStream_t stream) {
    const int M = 8192;   // B*T
    const int D = 1024, D3 = 3072, FF = 4096;

    const float* x      = (const float*)d_in[0];
    const float* ln1_g  = (const float*)d_in[1];
    const float* ln1_b  = (const float*)d_in[2];
    const float* W_ap   = (const float*)d_in[3];
    const float* b_ap   = (const float*)d_in[4];
    const float* W_qkv  = (const float*)d_in[5];
    const float* b_qkv  = (const float*)d_in[6];
    const float* W_proj = (const float*)d_in[7];
    const float* b_proj = (const float*)d_in[8];
    const float* ln2_g  = (const float*)d_in[9];
    const float* ln2_b  = (const float*)d_in[10];
    const float* W1     = (const float*)d_in[11];
    const float* b1     = (const float*)d_in[12];
    const float* W2     = (const float*)d_in[13];
    const float* b2     = (const float*)d_in[14];

    char* p = (char*)d_ws;
    auto carve = [&](size_t bytes) { char* r = p; p += (bytes + 255) & ~(size_t)255; return r; };
    u16*   WapT   = (u16*)carve((size_t)D * D * 2);
    u16*   WqkvT  = (u16*)carve((size_t)D * D3 * 2);
    u16*   WprojT = (u16*)carve((size_t)D * D * 2);
    u16*   W1T    = (u16*)carve((size_t)D * FF * 2);
    u16*   W2T    = (u16*)carve((size_t)FF * D * 2);
    u16*   aln    = (u16*)carve((size_t)M * D * 2);    // reused as gbuf
    u16*   a1     = (u16*)carve((size_t)M * D * 2);    // reused as obuf
    u16*   qkvb   = (u16*)carve((size_t)M * D3 * 2);
    float* hbuf   = (float*)carve((size_t)M * D * 4);
    u16*   f1     = (u16*)carve((size_t)M * FF * 2);
    float* maxkn  = (float*)carve(64 * 4);
    u16* gbuf = aln;
    u16* obuf = a1;
    u16* vtg  = f1;   // V^T [b,h,dim,2048] (16MB) overlaps f1: dead before W1 GEMM

    dim3 tb(32, 8);
    transpose_f32_bf16<<<dim3(D / 32, D / 32), tb, 0, stream>>>(W_ap, WapT, D, D);
    transpose_f32_bf16<<<dim3(D3 / 32, D / 32), tb, 0, stream>>>(W_qkv, WqkvT, D, D3);
    transpose_f32_bf16<<<dim3(D / 32, D / 32), tb, 0, stream>>>(W_proj, WprojT, D, D);
    transpose_f32_bf16<<<dim3(FF / 32, D / 32), tb, 0, stream>>>(W1, W1T, D, FF);
    transpose_f32_bf16<<<dim3(D / 32, FF / 32), tb, 0, stream>>>(W2, W2T, FF, D);

    // a = LN1(x)
    ln_kernel<false><<<M, 256, 0, stream>>>(x, ln1_g, ln1_b, aln);
    // a1 = a @ W_ap + b_ap
    gemm_kernel<1, 0, 0, 0><<<dim3(D / 128, M / 128), 256, 0, stream>>>(
        aln, WapT, b_ap, nullptr, a1, nullptr, M, D, D);
    // qkv = a1 @ W_qkv + b_qkv  (V third written transposed into vtg)
    gemm_kernel<1, 0, 0, 1><<<dim3(D3 / 128, M / 128), 256, 0, stream>>>(
        a1, WqkvT, b_qkv, nullptr, qkvb, vtg, M, D3, D);
    // per-(b,h) max K-norm for the softmax bound
    knorm_kernel<<<64, 256, 0, stream>>>(qkvb, maxkn);
    // o = attention(qkv, vtg)
    attn_kernel<<<dim3(64, 16), 256, 0, stream>>>(qkvb, vtg, maxkn, obuf);
    // h = x + o @ W_proj + b_proj   (fp32)
    gemm_kernel<0, 0, 1, 0><<<dim3(D / 128, M / 128), 256, 0, stream>>>(
        obuf, WprojT, b_proj, x, hbuf, nullptr, M, D, D);
    // g = gelu(LN2(h))
    ln_kernel<true><<<M, 256, 0, stream>>>(hbuf, ln2_g, ln2_b, gbuf);
    // f1 = gelu(g @ W1 + b1)
    gemm_kernel<1, 1, 0, 0><<<dim3(FF / 128, M / 128), 256, 0, stream>>>(
        gbuf, W1T, b1, nullptr, f1, nullptr, M, FF, D);
    // out = h + f1 @ W2 + b2   (fp32)
    gemm_kernel<0, 0, 1, 0><<<dim3(D / 128, M / 128), 256, 0, stream>>>(
        f1, W2T, b2, hbuf, (float*)d_out, nullptr, M, D, FF);
}